// Round 2
// baseline (1218.514 us; speedup 1.0000x reference)
//
#include <hip/hip_runtime.h>

// QuadraticAttention on MI355X — round 2: fp32 I/O (reference dtypes), fp32 vector math.
// Pipeline: [gemm_nt x3: q,k,v fp32 ws] -> [rmsnorm+rope in-place on q,k]
//           -> [attn: z = ((q.kT)/64)^2 (causal) @ v, fp32 ws]
//           -> [gemm_nt + residual -> d_out fp32]

typedef float vf4 __attribute__((ext_vector_type(4)));

// ---------------------------------------------------------------------------
// C[m][n] = sum_k A[m][k] * W[n][k]  (+ bias[n])  or (+ residual[m][n]) when ADD_RES
// A: M x K fp32 row-major, W: N x K fp32 row-major. 128x128x16 tiles,
// 256 threads, 8x8 microtile per thread. fp32 accumulate.
// ---------------------------------------------------------------------------
#define GBM 128
#define GBN 128
#define GBK 16

template<int ADD_RES>
__global__ __launch_bounds__(256) void gemm_nt(
    const float* __restrict__ A,
    const float* __restrict__ W,
    const float* __restrict__ bias,
    const float* __restrict__ resid,
    float* __restrict__ out,
    int M, int N, int K)
{
    __shared__ float As[GBK][GBM + 4];
    __shared__ float Ws[GBK][GBN + 4];
    const int tid = threadIdx.x;
    const int n0 = blockIdx.x * GBN;
    const int m0 = blockIdx.y * GBM;
    const int tx = tid & 15;
    const int ty = tid >> 4;

    float acc[8][8];
#pragma unroll
    for (int i = 0; i < 8; i++)
#pragma unroll
        for (int j = 0; j < 8; j++) acc[i][j] = 0.f;

    const int srow = tid >> 1;        // 0..127
    const int scol = (tid & 1) * 8;   // 0 or 8
    const float* Ap = A + (size_t)(m0 + srow) * K + scol;
    const float* Wp = W + (size_t)(n0 + srow) * K + scol;

    for (int kt = 0; kt < K; kt += GBK) {
        vf4 a0 = *(const vf4*)(Ap + kt);
        vf4 a1 = *(const vf4*)(Ap + kt + 4);
        vf4 w0 = *(const vf4*)(Wp + kt);
        vf4 w1 = *(const vf4*)(Wp + kt + 4);
#pragma unroll
        for (int i = 0; i < 4; i++) {
            As[scol + i][srow]     = a0[i];
            As[scol + 4 + i][srow] = a1[i];
            Ws[scol + i][srow]     = w0[i];
            Ws[scol + 4 + i][srow] = w1[i];
        }
        __syncthreads();
#pragma unroll
        for (int kk = 0; kk < GBK; kk++) {
            vf4 av0 = *(const vf4*)&As[kk][ty * 8];
            vf4 av1 = *(const vf4*)&As[kk][ty * 8 + 4];
            vf4 bv0 = *(const vf4*)&Ws[kk][tx * 8];
            vf4 bv1 = *(const vf4*)&Ws[kk][tx * 8 + 4];
            float a[8] = {av0[0], av0[1], av0[2], av0[3], av1[0], av1[1], av1[2], av1[3]};
            float b[8] = {bv0[0], bv0[1], bv0[2], bv0[3], bv1[0], bv1[1], bv1[2], bv1[3]};
#pragma unroll
            for (int i = 0; i < 8; i++)
#pragma unroll
                for (int j = 0; j < 8; j++) acc[i][j] += a[i] * b[j];
        }
        __syncthreads();
    }

    if (ADD_RES == 0) {
        float bs[8];
#pragma unroll
        for (int j = 0; j < 8; j++) bs[j] = bias[n0 + tx * 8 + j];
#pragma unroll
        for (int i = 0; i < 8; i++) {
            const int m = m0 + ty * 8 + i;
            float* orow = out + (size_t)m * N + n0 + tx * 8;
            vf4 o0, o1;
#pragma unroll
            for (int j = 0; j < 4; j++) o0[j] = acc[i][j] + bs[j];
#pragma unroll
            for (int j = 0; j < 4; j++) o1[j] = acc[i][4 + j] + bs[4 + j];
            *(vf4*)orow = o0;
            *(vf4*)(orow + 4) = o1;
        }
    } else {
#pragma unroll
        for (int i = 0; i < 8; i++) {
            const int m = m0 + ty * 8 + i;
            const float* rrow = resid + (size_t)m * N + n0 + tx * 8;
            float* orow = out + (size_t)m * N + n0 + tx * 8;
            vf4 r0 = *(const vf4*)rrow;
            vf4 r1 = *(const vf4*)(rrow + 4);
            vf4 o0, o1;
#pragma unroll
            for (int j = 0; j < 4; j++) o0[j] = acc[i][j] + r0[j];
#pragma unroll
            for (int j = 0; j < 4; j++) o1[j] = acc[i][4 + j] + r1[j];
            *(vf4*)orow = o0;
            *(vf4*)(orow + 4) = o1;
        }
    }
}

// ---------------------------------------------------------------------------
// In-place rmsnorm (per 64-dim head vector, eps=FLT_EPSILON) + interleaved
// RoPE with concatenated cache: angle(j) = t * 10000^{-(j mod 32)/32}.
// One wave per head-vector, 4 vectors/block. First half of grid: q, second: k.
// ---------------------------------------------------------------------------
__global__ __launch_bounds__(256) void rmsnorm_rope(
    float* __restrict__ qb, float* __restrict__ kb,
    const float* __restrict__ nw)
{
    const int tid = threadIdx.x;
    const int lane = tid & 63;
    const int wv = tid >> 6;
    const int half = gridDim.x >> 1;
    float* buf = (blockIdx.x < half) ? qb : kb;
    const int bx = (blockIdx.x < half) ? blockIdx.x : (blockIdx.x - half);
    const int vec = bx * 4 + wv;    // 0 .. M*16-1
    const int m = vec >> 4;         // token index
    const int h = vec & 15;
    const int t = m & 2047;         // position within sequence (S=2048)
    const size_t off = (size_t)m * 1024 + h * 64 + lane;

    float v = buf[off];
    float ss = v * v;
#pragma unroll
    for (int o = 1; o < 64; o <<= 1) ss += __shfl_xor(ss, o);
    const float scale = rsqrtf(ss * (1.0f / 64.0f) + 1.1920929e-07f);
    const float n = v * scale * nw[lane];
    const float partner = __shfl_xor(n, 1);
    const float rot = (lane & 1) ? partner : -partner; // even: -x[j+1], odd: +x[j-1]
    const float invf = expf(-(float)(lane & 31) * 0.28782313662425572f); // ln(1e4)/32
    const float ang = (float)t * invf;
    buf[off] = n * cosf(ang) + rot * sinf(ang);
}

// ---------------------------------------------------------------------------
// z[b,q,h,:] = sum_{k<=q} ((q.k)/64)^2 * v[k]   per head. 64x64 tiles.
// Block = (q-tile, b*16+h). KPs buffer is reused for K-tile then P-tile.
// ---------------------------------------------------------------------------
__global__ __launch_bounds__(256) void attn_sq(
    const float* __restrict__ q, const float* __restrict__ k,
    const float* __restrict__ v, float* __restrict__ z)
{
    __shared__ float Qs[64][68];   // [d][q]
    __shared__ float KPs[64][68];  // [d][k] during scores, then [k][q] for P
    __shared__ float Vs[64][68];   // [k][d]
    const int tid = threadIdx.x;
    const int qt = blockIdx.x;
    const int b = blockIdx.y >> 4;
    const int h = blockIdx.y & 15;
    const size_t base = ((size_t)b * 2048) * 1024 + (size_t)h * 64;

#pragma unroll
    for (int f = 0; f < 4; f++) {
        const int linear = tid + f * 256;
        const int r = linear >> 4;
        const int dq = (linear & 15) * 4;
        vf4 val = *(const vf4*)(q + base + (size_t)(qt * 64 + r) * 1024 + dq);
#pragma unroll
        for (int i = 0; i < 4; i++) Qs[dq + i][r] = val[i];
    }

    const int tx = tid & 15;
    const int ty = tid >> 4;
    float zacc[4][4];
#pragma unroll
    for (int i = 0; i < 4; i++)
#pragma unroll
        for (int j = 0; j < 4; j++) zacc[i][j] = 0.f;

    for (int kt = 0; kt <= qt; kt++) {
        __syncthreads(); // previous-iteration readers of KPs/Vs (and Qs stage) done
#pragma unroll
        for (int f = 0; f < 4; f++) {
            const int linear = tid + f * 256;
            const int r = linear >> 4;
            const int dq = (linear & 15) * 4;
            vf4 kvv = *(const vf4*)(k + base + (size_t)(kt * 64 + r) * 1024 + dq);
#pragma unroll
            for (int i = 0; i < 4; i++) KPs[dq + i][r] = kvv[i];
            vf4 vvv = *(const vf4*)(v + base + (size_t)(kt * 64 + r) * 1024 + dq);
            *(vf4*)&Vs[r][dq] = vvv;
        }
        __syncthreads();

        float s[4][4];
#pragma unroll
        for (int i = 0; i < 4; i++)
#pragma unroll
            for (int j = 0; j < 4; j++) s[i][j] = 0.f;
#pragma unroll 4
        for (int d = 0; d < 64; d++) {
            vf4 qv = *(const vf4*)&Qs[d][ty * 4];
            vf4 kv = *(const vf4*)&KPs[d][tx * 4];
#pragma unroll
            for (int i = 0; i < 4; i++)
#pragma unroll
                for (int j = 0; j < 4; j++) s[i][j] += qv[i] * kv[j];
        }
        __syncthreads(); // everyone's K reads done before KPs is overwritten by P

        const bool diag = (kt == qt);
#pragma unroll
        for (int i = 0; i < 4; i++)
#pragma unroll
            for (int j = 0; j < 4; j++) {
                const float sc = s[i][j] * (1.0f / 64.0f);
                float p = sc * sc;
                if (diag && (tx * 4 + j > ty * 4 + i)) p = 0.f; // strictly-upper masked
                KPs[tx * 4 + j][ty * 4 + i] = p; // store transposed: [k][q]
            }
        __syncthreads();

#pragma unroll 4
        for (int kk = 0; kk < 64; kk++) {
            vf4 pv = *(const vf4*)&KPs[kk][ty * 4];
            vf4 vv = *(const vf4*)&Vs[kk][tx * 4];
#pragma unroll
            for (int i = 0; i < 4; i++)
#pragma unroll
                for (int j = 0; j < 4; j++) zacc[i][j] += pv[i] * vv[j];
        }
    }

#pragma unroll
    for (int i = 0; i < 4; i++) {
        const int r = qt * 64 + ty * 4 + i;
        float* orow = z + base + (size_t)r * 1024 + tx * 4;
        vf4 ov;
#pragma unroll
        for (int j = 0; j < 4; j++) ov[j] = zacc[i][j];
        *(vf4*)orow = ov;
    }
}

// ---------------------------------------------------------------------------
extern "C" void kernel_launch(void* const* d_in, const int* in_sizes, int n_in,
                              void* d_out, int out_size, void* d_ws, size_t ws_size,
                              hipStream_t stream)
{
    const float* x  = (const float*)d_in[0];
    const float* Wq = (const float*)d_in[1];
    const float* bq = (const float*)d_in[2];
    const float* Wk = (const float*)d_in[3];
    const float* bk = (const float*)d_in[4];
    const float* Wv = (const float*)d_in[5];
    const float* bv = (const float*)d_in[6];
    const float* Wo = (const float*)d_in[7];
    const float* nw = (const float*)d_in[8];
    float* out = (float*)d_out;

    const int D = 1024;
    const int M = in_sizes[0] / D;        // B*S = 4096
    float* qf = (float*)d_ws;             // M*1024 fp32 each
    float* kf = qf + (size_t)M * D;
    float* vf = kf + (size_t)M * D;
    float* zf = vf + (size_t)M * D;

    dim3 blk(256);
    dim3 gg(D / GBN, M / GBM);            // (8, 32)

    gemm_nt<0><<<gg, blk, 0, stream>>>(x, Wq, bq, nullptr, qf, M, D, D);
    gemm_nt<0><<<gg, blk, 0, stream>>>(x, Wk, bk, nullptr, kf, M, D, D);
    gemm_nt<0><<<gg, blk, 0, stream>>>(x, Wv, bv, nullptr, vf, M, D, D);

    const int nrblocks = (M * 16 / 4) * 2; // q and k halves
    rmsnorm_rope<<<nrblocks, blk, 0, stream>>>(qf, kf, nw);

    dim3 ga(2048 / 64, (M / 2048) * 16);  // (32, B*16)
    attn_sq<<<ga, blk, 0, stream>>>(qf, kf, vf, zf);

    gemm_nt<1><<<gg, blk, 0, stream>>>(zf, Wo, nullptr, x, out, M, D, D);
}

// Round 3
// 637.483 us; speedup vs baseline: 1.9114x; 1.9114x over previous
//
#include <hip/hip_runtime.h>
#include <math.h>

// QuadraticAttention on MI355X — round 3: bf16 MFMA everywhere.
// cvt(x,W*) -> gemm_qkv (3 GEMMs + fused bias/rmsnorm/rope epilogue, writes bf16 q,k,vT)
// -> attn_mfma (causal ((QK^T)/64)^2 @ V via MFMA, vT pre-transposed) -> gemm_out (+x resid, fp32 out)

typedef float  f32x4  __attribute__((ext_vector_type(4)));
typedef short  bf16x8 __attribute__((ext_vector_type(8)));
typedef float  vf4    __attribute__((ext_vector_type(4)));
typedef unsigned short u16x4 __attribute__((ext_vector_type(4)));

static __device__ __forceinline__ unsigned short f2bf(float f) {
    union { float f; unsigned int i; } c; c.f = f;
    unsigned int x = c.i;
    return (unsigned short)((x + 0x7fffu + ((x >> 16) & 1u)) >> 16);
}

// ---------------------------------------------------------------------------
// fp32 -> bf16 elementwise (RNE), vectorized x4
// ---------------------------------------------------------------------------
__global__ __launch_bounds__(256) void cvt_bf16(
    const float* __restrict__ src, unsigned short* __restrict__ dst, int n4)
{
    int i = blockIdx.x * 256 + threadIdx.x;
    if (i < n4) {
        vf4 v = *(const vf4*)(src + (size_t)i * 4);
        u16x4 o;
#pragma unroll
        for (int j = 0; j < 4; j++) o[j] = f2bf(v[j]);
        *(u16x4*)(dst + (size_t)i * 4) = o;
    }
}

// ---------------------------------------------------------------------------
// Fused QKV GEMM: C = x @ W^T + b, 128x128x32 tiles, 16x16x32 bf16 MFMA.
// z==0/1 (q/k): epilogue rmsnorm (per-head, eps=FLT_EPS) + RoPE, store bf16.
// z==2 (v):     store transposed per head: vT[((b*16+h)*64+d)*2048 + tok].
// LDS row stride 40 elems (80B, 16B-aligned, ~2-way banks).
// ---------------------------------------------------------------------------
#define RS 40

__global__ __launch_bounds__(256) void gemm_qkv(
    const unsigned short* __restrict__ xb,
    const unsigned short* __restrict__ Wqb,
    const unsigned short* __restrict__ Wkb,
    const unsigned short* __restrict__ Wvb,
    const float* __restrict__ bqf, const float* __restrict__ bkf, const float* __restrict__ bvf,
    const float* __restrict__ nw,
    unsigned short* __restrict__ qb, unsigned short* __restrict__ kb,
    unsigned short* __restrict__ vT, int M)
{
    const int K = 1024;
    __shared__ unsigned short As[128 * RS];
    __shared__ unsigned short Ws[128 * RS];
    const int tid = threadIdx.x;
    const int z = blockIdx.z;
    const unsigned short* Wb = (z == 0) ? Wqb : (z == 1) ? Wkb : Wvb;
    const float* bias = (z == 0) ? bqf : (z == 1) ? bkf : bvf;
    const int n0 = blockIdx.x * 128;
    const int m0 = blockIdx.y * 128;

    const int lane = tid & 63, wid = tid >> 6;
    const int wy = wid >> 1, wx = wid & 1;
    const int l15 = lane & 15, quad = lane >> 4;

    f32x4 acc[4][4] = {};

    for (int kt = 0; kt < K; kt += 32) {
        __syncthreads();
#pragma unroll
        for (int j = 0; j < 2; j++) {
            int u = tid + j * 256;
            int row = u >> 2, cb = u & 3;
            *(bf16x8*)&As[row * RS + cb * 8] =
                *(const bf16x8*)(xb + (size_t)(m0 + row) * K + kt + cb * 8);
            *(bf16x8*)&Ws[row * RS + cb * 8] =
                *(const bf16x8*)(Wb + (size_t)(n0 + row) * K + kt + cb * 8);
        }
        __syncthreads();
        bf16x8 af[4], bfr[4];
#pragma unroll
        for (int mi = 0; mi < 4; mi++)
            af[mi] = *(const bf16x8*)&As[(wy * 64 + mi * 16 + l15) * RS + quad * 8];
#pragma unroll
        for (int ni = 0; ni < 4; ni++)
            bfr[ni] = *(const bf16x8*)&Ws[(wx * 64 + ni * 16 + l15) * RS + quad * 8];
#pragma unroll
        for (int mi = 0; mi < 4; mi++)
#pragma unroll
            for (int ni = 0; ni < 4; ni++)
                acc[mi][ni] = __builtin_amdgcn_mfma_f32_16x16x32_bf16(
                    af[mi], bfr[ni], acc[mi][ni], 0, 0, 0);
    }

    // ---- epilogue ----
    float bs[4], nww[4];
#pragma unroll
    for (int ni = 0; ni < 4; ni++) {
        bs[ni] = bias[n0 + wx * 64 + ni * 16 + l15];
        nww[ni] = nw[ni * 16 + l15];
    }
#pragma unroll
    for (int mi = 0; mi < 4; mi++)
#pragma unroll
        for (int ni = 0; ni < 4; ni++)
#pragma unroll
            for (int r = 0; r < 4; r++) acc[mi][ni][r] += bs[ni];

    const int head = (n0 + wx * 64) >> 6;

    if (z < 2) {
        // rmsnorm: sum of squares over the wave's 64 cols (= one head) per row
        float s2[4][4];
#pragma unroll
        for (int mi = 0; mi < 4; mi++)
#pragma unroll
            for (int r = 0; r < 4; r++) {
                float s = 0.f;
#pragma unroll
                for (int ni = 0; ni < 4; ni++) s += acc[mi][ni][r] * acc[mi][ni][r];
                s2[mi][r] = s;
            }
#pragma unroll
        for (int off = 1; off < 16; off <<= 1)
#pragma unroll
            for (int mi = 0; mi < 4; mi++)
#pragma unroll
                for (int r = 0; r < 4; r++) s2[mi][r] += __shfl_xor(s2[mi][r], off);
#pragma unroll
        for (int mi = 0; mi < 4; mi++)
#pragma unroll
            for (int r = 0; r < 4; r++)
                s2[mi][r] = rsqrtf(s2[mi][r] * (1.0f / 64.0f) + 1.1920929e-07f);

        unsigned short* dst = (z == 0) ? qb : kb;
        const float lf0 = expf(-(float)l15 * 0.28782313662425572f);          // ln(1e4)/32
        const float lf1 = expf(-(float)(l15 + 16) * 0.28782313662425572f);
#pragma unroll
        for (int mi = 0; mi < 4; mi++)
#pragma unroll
            for (int r = 0; r < 4; r++) {
                const int m = m0 + wy * 64 + mi * 16 + quad * 4 + r;
                const float t = (float)(m & 2047);
                const float a0 = t * lf0, a1 = t * lf1;
                const float cs0 = cosf(a0), sn0 = sinf(a0);
                const float cs1 = cosf(a1), sn1 = sinf(a1);
#pragma unroll
                for (int ni = 0; ni < 4; ni++) {
                    float vn = acc[mi][ni][r] * s2[mi][r] * nww[ni];
                    float partner = __shfl_xor(vn, 1);
                    float rot = (lane & 1) ? partner : -partner;  // even: -x[c+1]; odd: +x[c-1]
                    float cs = (ni & 1) ? cs1 : cs0;
                    float sn = (ni & 1) ? sn1 : sn0;
                    dst[(size_t)m * 1024 + head * 64 + ni * 16 + l15] = f2bf(vn * cs + rot * sn);
                }
            }
    } else {
        // V: store transposed per head for clean PV staging
#pragma unroll
        for (int mi = 0; mi < 4; mi++)
#pragma unroll
            for (int r = 0; r < 4; r++) {
                const int m = m0 + wy * 64 + mi * 16 + quad * 4 + r;
                const int b = m >> 11, tok = m & 2047;
#pragma unroll
                for (int ni = 0; ni < 4; ni++) {
                    const int d = ni * 16 + l15;
                    vT[(((size_t)b * 16 + head) * 64 + d) * 2048 + tok] = f2bf(acc[mi][ni][r]);
                }
            }
    }
}

// ---------------------------------------------------------------------------
// Output GEMM: out = zb @ Wo^T + x (fp32 residual, fp32 out)
// ---------------------------------------------------------------------------
__global__ __launch_bounds__(256) void gemm_out(
    const unsigned short* __restrict__ zb,
    const unsigned short* __restrict__ Wob,
    const float* __restrict__ x, float* __restrict__ out, int M)
{
    const int K = 1024;
    __shared__ unsigned short As[128 * RS];
    __shared__ unsigned short Ws[128 * RS];
    const int tid = threadIdx.x;
    const int n0 = blockIdx.x * 128;
    const int m0 = blockIdx.y * 128;
    const int lane = tid & 63, wid = tid >> 6;
    const int wy = wid >> 1, wx = wid & 1;
    const int l15 = lane & 15, quad = lane >> 4;

    f32x4 acc[4][4] = {};
    for (int kt = 0; kt < K; kt += 32) {
        __syncthreads();
#pragma unroll
        for (int j = 0; j < 2; j++) {
            int u = tid + j * 256;
            int row = u >> 2, cb = u & 3;
            *(bf16x8*)&As[row * RS + cb * 8] =
                *(const bf16x8*)(zb + (size_t)(m0 + row) * K + kt + cb * 8);
            *(bf16x8*)&Ws[row * RS + cb * 8] =
                *(const bf16x8*)(Wob + (size_t)(n0 + row) * K + kt + cb * 8);
        }
        __syncthreads();
        bf16x8 af[4], bfr[4];
#pragma unroll
        for (int mi = 0; mi < 4; mi++)
            af[mi] = *(const bf16x8*)&As[(wy * 64 + mi * 16 + l15) * RS + quad * 8];
#pragma unroll
        for (int ni = 0; ni < 4; ni++)
            bfr[ni] = *(const bf16x8*)&Ws[(wx * 64 + ni * 16 + l15) * RS + quad * 8];
#pragma unroll
        for (int mi = 0; mi < 4; mi++)
#pragma unroll
            for (int ni = 0; ni < 4; ni++)
                acc[mi][ni] = __builtin_amdgcn_mfma_f32_16x16x32_bf16(
                    af[mi], bfr[ni], acc[mi][ni], 0, 0, 0);
    }
#pragma unroll
    for (int mi = 0; mi < 4; mi++)
#pragma unroll
        for (int ni = 0; ni < 4; ni++)
#pragma unroll
            for (int r = 0; r < 4; r++) {
                const int m = m0 + wy * 64 + mi * 16 + quad * 4 + r;
                const int n = n0 + wx * 64 + ni * 16 + l15;
                out[(size_t)m * 1024 + n] = acc[mi][ni][r] + x[(size_t)m * 1024 + n];
            }
}

// ---------------------------------------------------------------------------
// Causal quadratic attention, MFMA. Block: 128 q-rows of one (b,h); k-tiles of 64.
// S = Q K^T (NT); P = (S/64)^2 masked -> Pm (bf16, per-wave LDS region, no barrier);
// Z += P @ V via NT against pre-transposed vT tiles. All frag reads ds_read_b128.
// ---------------------------------------------------------------------------
__global__ __launch_bounds__(256) void attn_mfma(
    const unsigned short* __restrict__ qb, const unsigned short* __restrict__ kb,
    const unsigned short* __restrict__ vT, unsigned short* __restrict__ zb)
{
    __shared__ unsigned short Qs[128 * 72];
    __shared__ unsigned short Ks[64 * 72];
    __shared__ unsigned short Vs[64 * 72];   // Vt tile: rows d, cols k
    __shared__ unsigned short Pm[128 * 72];
    const int tid = threadIdx.x;
    const int qti = 15 - blockIdx.x;          // big tiles first
    const int bh = blockIdx.y;
    const int b = bh >> 4, h = bh & 15;
    const int lane = tid & 63, wq = tid >> 6;
    const int l15 = lane & 15, quad = lane >> 4;
    const size_t tokbase = (size_t)b * 2048;

#pragma unroll
    for (int j = 0; j < 4; j++) {
        int u = tid + j * 256;
        int row = u >> 3, cb = u & 7;
        *(bf16x8*)&Qs[row * 72 + cb * 8] =
            *(const bf16x8*)(qb + (tokbase + qti * 128 + row) * 1024 + h * 64 + cb * 8);
    }

    f32x4 zacc[2][4] = {};
    const int nkt = 2 * qti + 2;
    for (int kt = 0; kt < nkt; kt++) {
        __syncthreads();
#pragma unroll
        for (int j = 0; j < 2; j++) {
            int u = tid + j * 256;
            int row = u >> 3, cb = u & 7;
            *(bf16x8*)&Ks[row * 72 + cb * 8] =
                *(const bf16x8*)(kb + (tokbase + kt * 64 + row) * 1024 + h * 64 + cb * 8);
            *(bf16x8*)&Vs[row * 72 + cb * 8] =
                *(const bf16x8*)(vT + ((size_t)bh * 64 + row) * 2048 + kt * 64 + cb * 8);
        }
        __syncthreads();

        // S = Q K^T
        f32x4 sacc[2][4] = {};
#pragma unroll
        for (int ks = 0; ks < 2; ks++) {
            bf16x8 aq[2], bk4[4];
#pragma unroll
            for (int mi = 0; mi < 2; mi++)
                aq[mi] = *(const bf16x8*)&Qs[(wq * 32 + mi * 16 + l15) * 72 + ks * 32 + quad * 8];
#pragma unroll
            for (int kn = 0; kn < 4; kn++)
                bk4[kn] = *(const bf16x8*)&Ks[(kn * 16 + l15) * 72 + ks * 32 + quad * 8];
#pragma unroll
            for (int mi = 0; mi < 2; mi++)
#pragma unroll
                for (int kn = 0; kn < 4; kn++)
                    sacc[mi][kn] = __builtin_amdgcn_mfma_f32_16x16x32_bf16(
                        aq[mi], bk4[kn], sacc[mi][kn], 0, 0, 0);
        }

        // P = (S/64)^2, causal mask on diagonal tiles; per-wave Pm region
        const bool needmask = (kt >= 2 * qti);
#pragma unroll
        for (int mi = 0; mi < 2; mi++)
#pragma unroll
            for (int kn = 0; kn < 4; kn++)
#pragma unroll
                for (int r = 0; r < 4; r++) {
                    const int qrow = qti * 128 + wq * 32 + mi * 16 + quad * 4 + r;
                    const int kcol = kt * 64 + kn * 16 + l15;
                    float sc = sacc[mi][kn][r] * (1.0f / 64.0f);
                    float p = sc * sc;
                    if (needmask && kcol > qrow) p = 0.f;
                    Pm[(wq * 32 + mi * 16 + quad * 4 + r) * 72 + kn * 16 + l15] = f2bf(p);
                }

        // Z += P @ V  (A = Pm rows, B-frag from Vt tile: B[k][n=d] = Vt[d][k])
#pragma unroll
        for (int ks = 0; ks < 2; ks++) {
            bf16x8 ap[2], bv4[4];
#pragma unroll
            for (int mi = 0; mi < 2; mi++)
                ap[mi] = *(const bf16x8*)&Pm[(wq * 32 + mi * 16 + l15) * 72 + ks * 32 + quad * 8];
#pragma unroll
            for (int dn = 0; dn < 4; dn++)
                bv4[dn] = *(const bf16x8*)&Vs[(dn * 16 + l15) * 72 + ks * 32 + quad * 8];
#pragma unroll
            for (int mi = 0; mi < 2; mi++)
#pragma unroll
                for (int dn = 0; dn < 4; dn++)
                    zacc[mi][dn] = __builtin_amdgcn_mfma_f32_16x16x32_bf16(
                        ap[mi], bv4[dn], zacc[mi][dn], 0, 0, 0);
        }
    }

#pragma unroll
    for (int mi = 0; mi < 2; mi++)
#pragma unroll
        for (int dn = 0; dn < 4; dn++)
#pragma unroll
            for (int r = 0; r < 4; r++) {
                const int tok = qti * 128 + wq * 32 + mi * 16 + quad * 4 + r;
                zb[(tokbase + tok) * 1024 + h * 64 + dn * 16 + l15] = f2bf(zacc[mi][dn][r]);
            }
}

// ---------------------------------------------------------------------------
extern "C" void kernel_launch(void* const* d_in, const int* in_sizes, int n_in,
                              void* d_out, int out_size, void* d_ws, size_t ws_size,
                              hipStream_t stream)
{
    const float* x  = (const float*)d_in[0];
    const float* Wq = (const float*)d_in[1];
    const float* bq = (const float*)d_in[2];
    const float* Wk = (const float*)d_in[3];
    const float* bk = (const float*)d_in[4];
    const float* Wv = (const float*)d_in[5];
    const float* bv = (const float*)d_in[6];
    const float* Wo = (const float*)d_in[7];
    const float* nw = (const float*)d_in[8];
    float* out = (float*)d_out;

    const int D = 1024;
    const int M = in_sizes[0] / D;   // B*S = 4096

    unsigned short* xbb = (unsigned short*)d_ws;         // M*D
    unsigned short* Wqb = xbb + (size_t)M * D;           // D*D
    unsigned short* Wkb = Wqb + (size_t)D * D;
    unsigned short* Wvb = Wkb + (size_t)D * D;
    unsigned short* Wob = Wvb + (size_t)D * D;
    unsigned short* qbw = Wob + (size_t)D * D;           // M*D
    unsigned short* kbw = qbw + (size_t)M * D;
    unsigned short* vTw = kbw + (size_t)M * D;
    unsigned short* zbw = vTw + (size_t)M * D;

    const int nx4 = M * D / 4, nw4 = D * D / 4;
    cvt_bf16<<<(nx4 + 255) / 256, 256, 0, stream>>>(x, xbb, nx4);
    cvt_bf16<<<(nw4 + 255) / 256, 256, 0, stream>>>(Wq, Wqb, nw4);
    cvt_bf16<<<(nw4 + 255) / 256, 256, 0, stream>>>(Wk, Wkb, nw4);
    cvt_bf16<<<(nw4 + 255) / 256, 256, 0, stream>>>(Wv, Wvb, nw4);
    cvt_bf16<<<(nw4 + 255) / 256, 256, 0, stream>>>(Wo, Wob, nw4);

    gemm_qkv<<<dim3(D / 128, M / 128, 3), 256, 0, stream>>>(
        xbb, Wqb, Wkb, Wvb, bq, bk, bv, nw, qbw, kbw, vTw, M);

    attn_mfma<<<dim3(16, (M / 2048) * 16), 256, 0, stream>>>(qbw, kbw, vTw, zbw);

    gemm_out<<<dim3(D / 128, M / 128), 256, 0, stream>>>(zbw, Wob, x, out, M);
}

// Round 4
// 581.679 us; speedup vs baseline: 2.0948x; 1.0959x over previous
//
#include <hip/hip_runtime.h>
#include <math.h>

// QuadraticAttention on MI355X — round 4: fix HBM write amplification.
// All global epilogue stores now go through LDS staging -> bf16x8 (16B/lane)
// contiguous line-aligned stores. Round 3 had 2B scattered stores costing
// 1.6 GB of HBM writes in gemm_qkv (vs 24 MB algorithmic).

typedef float  f32x4  __attribute__((ext_vector_type(4)));
typedef short  bf16x8 __attribute__((ext_vector_type(8)));
typedef float  vf4    __attribute__((ext_vector_type(4)));
typedef unsigned short u16x4 __attribute__((ext_vector_type(4)));

static __device__ __forceinline__ unsigned short f2bf(float f) {
    union { float f; unsigned int i; } c; c.f = f;
    unsigned int x = c.i;
    return (unsigned short)((x + 0x7fffu + ((x >> 16) & 1u)) >> 16);
}

// ---------------------------------------------------------------------------
__global__ __launch_bounds__(256) void cvt_bf16(
    const float* __restrict__ src, unsigned short* __restrict__ dst, int n4)
{
    int i = blockIdx.x * 256 + threadIdx.x;
    if (i < n4) {
        vf4 v = *(const vf4*)(src + (size_t)i * 4);
        u16x4 o;
#pragma unroll
        for (int j = 0; j < 4; j++) o[j] = f2bf(v[j]);
        *(u16x4*)(dst + (size_t)i * 4) = o;
    }
}

// ---------------------------------------------------------------------------
// Fused QKV GEMM: C = x @ W^T + b, 128x128x32 tiles, 16x16x32 bf16 MFMA.
// z==0/1 (q/k): epilogue rmsnorm + RoPE; z==2 (v): transposed per-head store.
// Output staged in LDS (stride 136 elem = 272B, 16B-aligned), stored bf16x8.
// ---------------------------------------------------------------------------
#define RS 40
#define SS 136   // stage row stride (elems); 128 cols + pad, 16B-aligned

__global__ __launch_bounds__(256) void gemm_qkv(
    const unsigned short* __restrict__ xb,
    const unsigned short* __restrict__ Wqb,
    const unsigned short* __restrict__ Wkb,
    const unsigned short* __restrict__ Wvb,
    const float* __restrict__ bqf, const float* __restrict__ bkf, const float* __restrict__ bvf,
    const float* __restrict__ nw,
    unsigned short* __restrict__ qb, unsigned short* __restrict__ kb,
    unsigned short* __restrict__ vT, int M)
{
    const int K = 1024;
    __shared__ unsigned short smem[128 * SS];     // 34816 B; aliases As|Ws then stage
    unsigned short* As = smem;                    // 128*RS = 5120 elem
    unsigned short* Ws = smem + 128 * RS;         // 5120 elem
    const int tid = threadIdx.x;
    const int z = blockIdx.z;
    const unsigned short* Wb = (z == 0) ? Wqb : (z == 1) ? Wkb : Wvb;
    const float* bias = (z == 0) ? bqf : (z == 1) ? bkf : bvf;
    const int n0 = blockIdx.x * 128;
    const int m0 = blockIdx.y * 128;

    const int lane = tid & 63, wid = tid >> 6;
    const int wy = wid >> 1, wx = wid & 1;
    const int l15 = lane & 15, quad = lane >> 4;

    f32x4 acc[4][4] = {};

    for (int kt = 0; kt < K; kt += 32) {
        __syncthreads();
#pragma unroll
        for (int j = 0; j < 2; j++) {
            int u = tid + j * 256;
            int row = u >> 2, cb = u & 3;
            *(bf16x8*)&As[row * RS + cb * 8] =
                *(const bf16x8*)(xb + (size_t)(m0 + row) * K + kt + cb * 8);
            *(bf16x8*)&Ws[row * RS + cb * 8] =
                *(const bf16x8*)(Wb + (size_t)(n0 + row) * K + kt + cb * 8);
        }
        __syncthreads();
        bf16x8 af[4], bfr[4];
#pragma unroll
        for (int mi = 0; mi < 4; mi++)
            af[mi] = *(const bf16x8*)&As[(wy * 64 + mi * 16 + l15) * RS + quad * 8];
#pragma unroll
        for (int ni = 0; ni < 4; ni++)
            bfr[ni] = *(const bf16x8*)&Ws[(wx * 64 + ni * 16 + l15) * RS + quad * 8];
#pragma unroll
        for (int mi = 0; mi < 4; mi++)
#pragma unroll
            for (int ni = 0; ni < 4; ni++)
                acc[mi][ni] = __builtin_amdgcn_mfma_f32_16x16x32_bf16(
                    af[mi], bfr[ni], acc[mi][ni], 0, 0, 0);
    }
    __syncthreads();   // all MFMA LDS reads done before smem is reused as stage

    // ---- epilogue: compute into LDS stage ----
    float bs[4], nww[4];
#pragma unroll
    for (int ni = 0; ni < 4; ni++) {
        bs[ni] = bias[n0 + wx * 64 + ni * 16 + l15];
        nww[ni] = nw[ni * 16 + l15];
    }
#pragma unroll
    for (int mi = 0; mi < 4; mi++)
#pragma unroll
        for (int ni = 0; ni < 4; ni++)
#pragma unroll
            for (int r = 0; r < 4; r++) acc[mi][ni][r] += bs[ni];

    if (z < 2) {
        float s2[4][4];
#pragma unroll
        for (int mi = 0; mi < 4; mi++)
#pragma unroll
            for (int r = 0; r < 4; r++) {
                float s = 0.f;
#pragma unroll
                for (int ni = 0; ni < 4; ni++) s += acc[mi][ni][r] * acc[mi][ni][r];
                s2[mi][r] = s;
            }
#pragma unroll
        for (int off = 1; off < 16; off <<= 1)
#pragma unroll
            for (int mi = 0; mi < 4; mi++)
#pragma unroll
                for (int r = 0; r < 4; r++) s2[mi][r] += __shfl_xor(s2[mi][r], off);
#pragma unroll
        for (int mi = 0; mi < 4; mi++)
#pragma unroll
            for (int r = 0; r < 4; r++)
                s2[mi][r] = rsqrtf(s2[mi][r] * (1.0f / 64.0f) + 1.1920929e-07f);

        const float lf0 = expf(-(float)l15 * 0.28782313662425572f);          // ln(1e4)/32
        const float lf1 = expf(-(float)(l15 + 16) * 0.28782313662425572f);
#pragma unroll
        for (int mi = 0; mi < 4; mi++)
#pragma unroll
            for (int r = 0; r < 4; r++) {
                const int mrow = wy * 64 + mi * 16 + quad * 4 + r;
                const float t = (float)((m0 + mrow) & 2047);
                const float a0 = t * lf0, a1 = t * lf1;
                const float cs0 = cosf(a0), sn0 = sinf(a0);
                const float cs1 = cosf(a1), sn1 = sinf(a1);
#pragma unroll
                for (int ni = 0; ni < 4; ni++) {
                    float vn = acc[mi][ni][r] * s2[mi][r] * nww[ni];
                    float partner = __shfl_xor(vn, 1);
                    float rot = (lane & 1) ? partner : -partner;
                    float cs = (ni & 1) ? cs1 : cs0;
                    float sn = (ni & 1) ? sn1 : sn0;
                    smem[mrow * SS + wx * 64 + ni * 16 + l15] = f2bf(vn * cs + rot * sn);
                }
            }
        __syncthreads();
        unsigned short* dst = (z == 0) ? qb : kb;
#pragma unroll
        for (int it = 0; it < 8; it++) {
            const int linear = tid + it * 256;
            const int row = linear >> 4, cb = linear & 15;
            *(bf16x8*)(dst + (size_t)(m0 + row) * 1024 + n0 + cb * 8) =
                *(const bf16x8*)&smem[row * SS + cb * 8];
        }
    } else {
        // stage transposed: stage[n_local][m_local]
#pragma unroll
        for (int mi = 0; mi < 4; mi++)
#pragma unroll
            for (int r = 0; r < 4; r++) {
                const int mrow = wy * 64 + mi * 16 + quad * 4 + r;
#pragma unroll
                for (int ni = 0; ni < 4; ni++)
                    smem[(wx * 64 + ni * 16 + l15) * SS + mrow] = f2bf(acc[mi][ni][r]);
            }
        __syncthreads();
        const int b = m0 >> 11, tok0 = m0 & 2047;
#pragma unroll
        for (int it = 0; it < 8; it++) {
            const int linear = tid + it * 256;
            const int rowd = linear >> 4, cb = linear & 15;  // rowd: n_local 0..127
            const int head_g = (n0 >> 6) + (rowd >> 6);
            const int d = rowd & 63;
            *(bf16x8*)(vT + (((size_t)b * 16 + head_g) * 64 + d) * 2048 + tok0 + cb * 8) =
                *(const bf16x8*)&smem[rowd * SS + cb * 8];
        }
    }
}

// ---------------------------------------------------------------------------
// Output GEMM: out = zb @ Wo^T + x (fp32 residual, fp32 out; 64B-contig stores)
// ---------------------------------------------------------------------------
__global__ __launch_bounds__(256) void gemm_out(
    const unsigned short* __restrict__ zb,
    const unsigned short* __restrict__ Wob,
    const float* __restrict__ x, float* __restrict__ out, int M)
{
    const int K = 1024;
    __shared__ unsigned short As[128 * RS];
    __shared__ unsigned short Ws[128 * RS];
    const int tid = threadIdx.x;
    const int n0 = blockIdx.x * 128;
    const int m0 = blockIdx.y * 128;
    const int lane = tid & 63, wid = tid >> 6;
    const int wy = wid >> 1, wx = wid & 1;
    const int l15 = lane & 15, quad = lane >> 4;

    f32x4 acc[4][4] = {};
    for (int kt = 0; kt < K; kt += 32) {
        __syncthreads();
#pragma unroll
        for (int j = 0; j < 2; j++) {
            int u = tid + j * 256;
            int row = u >> 2, cb = u & 3;
            *(bf16x8*)&As[row * RS + cb * 8] =
                *(const bf16x8*)(zb + (size_t)(m0 + row) * K + kt + cb * 8);
            *(bf16x8*)&Ws[row * RS + cb * 8] =
                *(const bf16x8*)(Wob + (size_t)(n0 + row) * K + kt + cb * 8);
        }
        __syncthreads();
        bf16x8 af[4], bfr[4];
#pragma unroll
        for (int mi = 0; mi < 4; mi++)
            af[mi] = *(const bf16x8*)&As[(wy * 64 + mi * 16 + l15) * RS + quad * 8];
#pragma unroll
        for (int ni = 0; ni < 4; ni++)
            bfr[ni] = *(const bf16x8*)&Ws[(wx * 64 + ni * 16 + l15) * RS + quad * 8];
#pragma unroll
        for (int mi = 0; mi < 4; mi++)
#pragma unroll
            for (int ni = 0; ni < 4; ni++)
                acc[mi][ni] = __builtin_amdgcn_mfma_f32_16x16x32_bf16(
                    af[mi], bfr[ni], acc[mi][ni], 0, 0, 0);
    }
#pragma unroll
    for (int mi = 0; mi < 4; mi++)
#pragma unroll
        for (int ni = 0; ni < 4; ni++)
#pragma unroll
            for (int r = 0; r < 4; r++) {
                const int m = m0 + wy * 64 + mi * 16 + quad * 4 + r;
                const int n = n0 + wx * 64 + ni * 16 + l15;
                out[(size_t)m * 1024 + n] = acc[mi][ni][r] + x[(size_t)m * 1024 + n];
            }
}

// ---------------------------------------------------------------------------
// Causal quadratic attention, MFMA. z-store staged per-wave in Pm -> bf16x8.
// ---------------------------------------------------------------------------
__global__ __launch_bounds__(256) void attn_mfma(
    const unsigned short* __restrict__ qb, const unsigned short* __restrict__ kb,
    const unsigned short* __restrict__ vT, unsigned short* __restrict__ zb)
{
    __shared__ unsigned short Qs[128 * 72];
    __shared__ unsigned short Ks[64 * 72];
    __shared__ unsigned short Vs[64 * 72];
    __shared__ unsigned short Pm[128 * 72];
    const int tid = threadIdx.x;
    const int qti = 15 - blockIdx.x;          // big tiles first
    const int bh = blockIdx.y;
    const int b = bh >> 4, h = bh & 15;
    const int lane = tid & 63, wq = tid >> 6;
    const int l15 = lane & 15, quad = lane >> 4;
    const size_t tokbase = (size_t)b * 2048;

#pragma unroll
    for (int j = 0; j < 4; j++) {
        int u = tid + j * 256;
        int row = u >> 3, cb = u & 7;
        *(bf16x8*)&Qs[row * 72 + cb * 8] =
            *(const bf16x8*)(qb + (tokbase + qti * 128 + row) * 1024 + h * 64 + cb * 8);
    }

    f32x4 zacc[2][4] = {};
    const int nkt = 2 * qti + 2;
    for (int kt = 0; kt < nkt; kt++) {
        __syncthreads();
#pragma unroll
        for (int j = 0; j < 2; j++) {
            int u = tid + j * 256;
            int row = u >> 3, cb = u & 7;
            *(bf16x8*)&Ks[row * 72 + cb * 8] =
                *(const bf16x8*)(kb + (tokbase + kt * 64 + row) * 1024 + h * 64 + cb * 8);
            *(bf16x8*)&Vs[row * 72 + cb * 8] =
                *(const bf16x8*)(vT + ((size_t)bh * 64 + row) * 2048 + kt * 64 + cb * 8);
        }
        __syncthreads();

        f32x4 sacc[2][4] = {};
#pragma unroll
        for (int ks = 0; ks < 2; ks++) {
            bf16x8 aq[2], bk4[4];
#pragma unroll
            for (int mi = 0; mi < 2; mi++)
                aq[mi] = *(const bf16x8*)&Qs[(wq * 32 + mi * 16 + l15) * 72 + ks * 32 + quad * 8];
#pragma unroll
            for (int kn = 0; kn < 4; kn++)
                bk4[kn] = *(const bf16x8*)&Ks[(kn * 16 + l15) * 72 + ks * 32 + quad * 8];
#pragma unroll
            for (int mi = 0; mi < 2; mi++)
#pragma unroll
                for (int kn = 0; kn < 4; kn++)
                    sacc[mi][kn] = __builtin_amdgcn_mfma_f32_16x16x32_bf16(
                        aq[mi], bk4[kn], sacc[mi][kn], 0, 0, 0);
        }

        const bool needmask = (kt >= 2 * qti);
#pragma unroll
        for (int mi = 0; mi < 2; mi++)
#pragma unroll
            for (int kn = 0; kn < 4; kn++)
#pragma unroll
                for (int r = 0; r < 4; r++) {
                    const int qrow = qti * 128 + wq * 32 + mi * 16 + quad * 4 + r;
                    const int kcol = kt * 64 + kn * 16 + l15;
                    float sc = sacc[mi][kn][r] * (1.0f / 64.0f);
                    float p = sc * sc;
                    if (needmask && kcol > qrow) p = 0.f;
                    Pm[(wq * 32 + mi * 16 + quad * 4 + r) * 72 + kn * 16 + l15] = f2bf(p);
                }

#pragma unroll
        for (int ks = 0; ks < 2; ks++) {
            bf16x8 ap[2], bv4[4];
#pragma unroll
            for (int mi = 0; mi < 2; mi++)
                ap[mi] = *(const bf16x8*)&Pm[(wq * 32 + mi * 16 + l15) * 72 + ks * 32 + quad * 8];
#pragma unroll
            for (int dn = 0; dn < 4; dn++)
                bv4[dn] = *(const bf16x8*)&Vs[(dn * 16 + l15) * 72 + ks * 32 + quad * 8];
#pragma unroll
            for (int mi = 0; mi < 2; mi++)
#pragma unroll
                for (int dn = 0; dn < 4; dn++)
                    zacc[mi][dn] = __builtin_amdgcn_mfma_f32_16x16x32_bf16(
                        ap[mi], bv4[dn], zacc[mi][dn], 0, 0, 0);
        }
    }

    // stage z into wave-private Pm rows, then 16B contiguous stores
#pragma unroll
    for (int mi = 0; mi < 2; mi++)
#pragma unroll
        for (int dn = 0; dn < 4; dn++)
#pragma unroll
            for (int r = 0; r < 4; r++)
                Pm[(wq * 32 + mi * 16 + quad * 4 + r) * 72 + dn * 16 + l15] =
                    f2bf(zacc[mi][dn][r]);
#pragma unroll
    for (int it = 0; it < 4; it++) {
        const int linear = it * 64 + lane;
        const int row = linear >> 3, cb = linear & 7;   // row 0..31, 8 segs of 8
        *(bf16x8*)(zb + (tokbase + qti * 128 + wq * 32 + row) * 1024 + h * 64 + cb * 8) =
            *(const bf16x8*)&Pm[(wq * 32 + row) * 72 + cb * 8];
    }
}

// ---------------------------------------------------------------------------
extern "C" void kernel_launch(void* const* d_in, const int* in_sizes, int n_in,
                              void* d_out, int out_size, void* d_ws, size_t ws_size,
                              hipStream_t stream)
{
    const float* x  = (const float*)d_in[0];
    const float* Wq = (const float*)d_in[1];
    const float* bq = (const float*)d_in[2];
    const float* Wk = (const float*)d_in[3];
    const float* bk = (const float*)d_in[4];
    const float* Wv = (const float*)d_in[5];
    const float* bv = (const float*)d_in[6];
    const float* Wo = (const float*)d_in[7];
    const float* nw = (const float*)d_in[8];
    float* out = (float*)d_out;

    const int D = 1024;
    const int M = in_sizes[0] / D;   // B*S = 4096

    unsigned short* xbb = (unsigned short*)d_ws;         // M*D
    unsigned short* Wqb = xbb + (size_t)M * D;           // D*D
    unsigned short* Wkb = Wqb + (size_t)D * D;
    unsigned short* Wvb = Wkb + (size_t)D * D;
    unsigned short* Wob = Wvb + (size_t)D * D;
    unsigned short* qbw = Wob + (size_t)D * D;           // M*D
    unsigned short* kbw = qbw + (size_t)M * D;
    unsigned short* vTw = kbw + (size_t)M * D;
    unsigned short* zbw = vTw + (size_t)M * D;

    const int nx4 = M * D / 4, nw4 = D * D / 4;
    cvt_bf16<<<(nx4 + 255) / 256, 256, 0, stream>>>(x, xbb, nx4);
    cvt_bf16<<<(nw4 + 255) / 256, 256, 0, stream>>>(Wq, Wqb, nw4);
    cvt_bf16<<<(nw4 + 255) / 256, 256, 0, stream>>>(Wk, Wkb, nw4);
    cvt_bf16<<<(nw4 + 255) / 256, 256, 0, stream>>>(Wv, Wvb, nw4);
    cvt_bf16<<<(nw4 + 255) / 256, 256, 0, stream>>>(Wo, Wob, nw4);

    gemm_qkv<<<dim3(D / 128, M / 128, 3), 256, 0, stream>>>(
        xbb, Wqb, Wkb, Wvb, bq, bk, bv, nw, qbw, kbw, vTw, M);

    attn_mfma<<<dim3(16, (M / 2048) * 16), 256, 0, stream>>>(qbw, kbw, vTw, zbw);

    gemm_out<<<dim3(D / 128, M / 128), 256, 0, stream>>>(zbw, Wob, x, out, M);
}

// Round 5
// 263.645 us; speedup vs baseline: 4.6218x; 2.2063x over previous
//
#include <hip/hip_runtime.h>
#include <math.h>

// QuadraticAttention on MI355X — round 5: kill accumulator scratch spill.
// Round 4 evidence: gemm_qkv WRITE_SIZE 1.46 GB ≈ 196608 thr × 32 K-iters ×
// 256 B = the f32x4 acc[4][4] aggregate being spilled to scratch every
// iteration (VGPR_Count=88 < working set). Fix: de-aggregate ALL MFMA
// accumulators/fragments into named registers via macros. Indexing identical
// to round 4 (which passed, absmax 0.031).

typedef float  f32x4  __attribute__((ext_vector_type(4)));
typedef short  bf16x8 __attribute__((ext_vector_type(8)));
typedef float  vf4    __attribute__((ext_vector_type(4)));
typedef unsigned short u16x4 __attribute__((ext_vector_type(4)));

static __device__ __forceinline__ unsigned short f2bf(float f) {
    union { float f; unsigned int i; } c; c.f = f;
    unsigned int x = c.i;
    return (unsigned short)((x + 0x7fffu + ((x >> 16) & 1u)) >> 16);
}
static __device__ __forceinline__ f32x4 shfl_xor4(f32x4 v, int m) {
    f32x4 r;
    r[0] = __shfl_xor(v[0], m); r[1] = __shfl_xor(v[1], m);
    r[2] = __shfl_xor(v[2], m); r[3] = __shfl_xor(v[3], m);
    return r;
}
static __device__ __forceinline__ f32x4 rsq4(f32x4 v) {
    f32x4 r;
#pragma unroll
    for (int i = 0; i < 4; i++) r[i] = rsqrtf(v[i] * (1.0f / 64.0f) + 1.1920929e-07f);
    return r;
}

#define FOR_M(X)  X(0) X(1) X(2) X(3)
#define FOR_MN(X) X(0,0) X(0,1) X(0,2) X(0,3) X(1,0) X(1,1) X(1,2) X(1,3) \
                  X(2,0) X(2,1) X(2,2) X(2,3) X(3,0) X(3,1) X(3,2) X(3,3)
#define FOR_MN2(X) X(0,0) X(0,1) X(0,2) X(0,3) X(1,0) X(1,1) X(1,2) X(1,3)

// ---------------------------------------------------------------------------
__global__ __launch_bounds__(256) void cvt_bf16(
    const float* __restrict__ src, unsigned short* __restrict__ dst, int n4)
{
    int i = blockIdx.x * 256 + threadIdx.x;
    if (i < n4) {
        vf4 v = *(const vf4*)(src + (size_t)i * 4);
        u16x4 o;
#pragma unroll
        for (int j = 0; j < 4; j++) o[j] = f2bf(v[j]);
        *(u16x4*)(dst + (size_t)i * 4) = o;
    }
}

// ---------------------------------------------------------------------------
#define RS 40
#define SS 136

// shared GEMM-core macros (named registers)
#define G_DECL_ACC(mi,ni) f32x4 c##mi##ni = {0.f, 0.f, 0.f, 0.f};
#define G_DECL_A(mi) bf16x8 a##mi = *(const bf16x8*)&As[(wy * 64 + (mi) * 16 + l15) * RS + quad * 8];
#define G_DECL_B(ni) bf16x8 b##ni = *(const bf16x8*)&Ws[(wx * 64 + (ni) * 16 + l15) * RS + quad * 8];
#define G_MFMA(mi,ni) c##mi##ni = __builtin_amdgcn_mfma_f32_16x16x32_bf16(a##mi, b##ni, c##mi##ni, 0, 0, 0);

__global__ __launch_bounds__(256) void gemm_qkv(
    const unsigned short* __restrict__ xb,
    const unsigned short* __restrict__ Wqb,
    const unsigned short* __restrict__ Wkb,
    const unsigned short* __restrict__ Wvb,
    const float* __restrict__ bqf, const float* __restrict__ bkf, const float* __restrict__ bvf,
    const float* __restrict__ nwp,
    unsigned short* __restrict__ qb, unsigned short* __restrict__ kb,
    unsigned short* __restrict__ vT, int M)
{
    const int K = 1024;
    __shared__ unsigned short smem[128 * SS];
    unsigned short* As = smem;
    unsigned short* Ws = smem + 128 * RS;
    const int tid = threadIdx.x;
    const int z = blockIdx.z;
    const unsigned short* Wb = (z == 0) ? Wqb : (z == 1) ? Wkb : Wvb;
    const float* bias = (z == 0) ? bqf : (z == 1) ? bkf : bvf;
    const int n0 = blockIdx.x * 128;
    const int m0 = blockIdx.y * 128;
    const int lane = tid & 63, wid = tid >> 6;
    const int wy = wid >> 1, wx = wid & 1;
    const int l15 = lane & 15, quad = lane >> 4;

    FOR_MN(G_DECL_ACC)

    for (int kt = 0; kt < K; kt += 32) {
        __syncthreads();
#pragma unroll
        for (int j = 0; j < 2; j++) {
            int u = tid + j * 256;
            int row = u >> 2, cb = u & 3;
            *(bf16x8*)&As[row * RS + cb * 8] =
                *(const bf16x8*)(xb + (size_t)(m0 + row) * K + kt + cb * 8);
            *(bf16x8*)&Ws[row * RS + cb * 8] =
                *(const bf16x8*)(Wb + (size_t)(n0 + row) * K + kt + cb * 8);
        }
        __syncthreads();
        FOR_M(G_DECL_A)
        FOR_M(G_DECL_B)
        FOR_MN(G_MFMA)
    }
    __syncthreads();   // all MFMA LDS reads done before smem is reused as stage

    // ---- epilogue ----
#define G_DECL_BIAS(ni) float bs##ni = bias[n0 + wx * 64 + (ni) * 16 + l15]; \
                        float nww##ni = nwp[(ni) * 16 + l15];
    FOR_M(G_DECL_BIAS)
#define G_ADD_BIAS(mi,ni) c##mi##ni = c##mi##ni + bs##ni;
    FOR_MN(G_ADD_BIAS)

    const int head = (n0 + wx * 64) >> 6;

    if (z < 2) {
#define G_SUMSQ(mi) f32x4 s2_##mi = c##mi##0 * c##mi##0 + c##mi##1 * c##mi##1 + \
                                    c##mi##2 * c##mi##2 + c##mi##3 * c##mi##3;
        FOR_M(G_SUMSQ)
#define G_RED(mi) s2_##mi = s2_##mi + shfl_xor4(s2_##mi, 1); \
                  s2_##mi = s2_##mi + shfl_xor4(s2_##mi, 2); \
                  s2_##mi = s2_##mi + shfl_xor4(s2_##mi, 4); \
                  s2_##mi = s2_##mi + shfl_xor4(s2_##mi, 8); \
                  s2_##mi = rsq4(s2_##mi);
        FOR_M(G_RED)

        const float lf0 = expf(-(float)l15 * 0.28782313662425572f);          // ln(1e4)/32
        const float lf1 = expf(-(float)(l15 + 16) * 0.28782313662425572f);

#define G_ROPE_ONE(mi,ni,CS,SN) { \
            float vn = c##mi##ni[r] * s2v[r] * nww##ni; \
            float pt = __shfl_xor(vn, 1); \
            float rot = (lane & 1) ? pt : -pt; \
            smem[mrow * SS + wx * 64 + (ni) * 16 + l15] = f2bf(vn * (CS) + rot * (SN)); }
#define G_ROPE_MI(mi) { f32x4 s2v = s2_##mi; \
            _Pragma("unroll") \
            for (int r = 0; r < 4; r++) { \
                const int mrow = wy * 64 + (mi) * 16 + quad * 4 + r; \
                const float t = (float)((m0 + mrow) & 2047); \
                const float a0 = t * lf0, a1 = t * lf1; \
                const float cs0 = cosf(a0), sn0 = sinf(a0); \
                const float cs1 = cosf(a1), sn1 = sinf(a1); \
                G_ROPE_ONE(mi,0,cs0,sn0) G_ROPE_ONE(mi,1,cs1,sn1) \
                G_ROPE_ONE(mi,2,cs0,sn0) G_ROPE_ONE(mi,3,cs1,sn1) } }
        FOR_M(G_ROPE_MI)

        __syncthreads();
        unsigned short* dst = (z == 0) ? qb : kb;
#pragma unroll
        for (int it = 0; it < 8; it++) {
            const int linear = tid + it * 256;
            const int row = linear >> 4, cb = linear & 15;
            *(bf16x8*)(dst + (size_t)(m0 + row) * 1024 + n0 + cb * 8) =
                *(const bf16x8*)&smem[row * SS + cb * 8];
        }
    } else {
#define G_VST(mi,ni) { _Pragma("unroll") \
            for (int r = 0; r < 4; r++) { \
                const int mrow = wy * 64 + (mi) * 16 + quad * 4 + r; \
                smem[(wx * 64 + (ni) * 16 + l15) * SS + mrow] = f2bf(c##mi##ni[r]); } }
        FOR_MN(G_VST)
        __syncthreads();
        const int b = m0 >> 11, tok0 = m0 & 2047;
#pragma unroll
        for (int it = 0; it < 8; it++) {
            const int linear = tid + it * 256;
            const int rowd = linear >> 4, cb = linear & 15;
            const int head_g = (n0 >> 6) + (rowd >> 6);
            const int d = rowd & 63;
            *(bf16x8*)(vT + (((size_t)b * 16 + head_g) * 64 + d) * 2048 + tok0 + cb * 8) =
                *(const bf16x8*)&smem[rowd * SS + cb * 8];
        }
    }
}

// ---------------------------------------------------------------------------
__global__ __launch_bounds__(256) void gemm_out(
    const unsigned short* __restrict__ zb,
    const unsigned short* __restrict__ Wob,
    const float* __restrict__ x, float* __restrict__ out, int M)
{
    const int K = 1024;
    __shared__ unsigned short As[128 * RS];
    __shared__ unsigned short Ws[128 * RS];
    const int tid = threadIdx.x;
    const int n0 = blockIdx.x * 128;
    const int m0 = blockIdx.y * 128;
    const int lane = tid & 63, wid = tid >> 6;
    const int wy = wid >> 1, wx = wid & 1;
    const int l15 = lane & 15, quad = lane >> 4;

    FOR_MN(G_DECL_ACC)

    for (int kt = 0; kt < K; kt += 32) {
        __syncthreads();
#pragma unroll
        for (int j = 0; j < 2; j++) {
            int u = tid + j * 256;
            int row = u >> 2, cb = u & 3;
            *(bf16x8*)&As[row * RS + cb * 8] =
                *(const bf16x8*)(zb + (size_t)(m0 + row) * K + kt + cb * 8);
            *(bf16x8*)&Ws[row * RS + cb * 8] =
                *(const bf16x8*)(Wob + (size_t)(n0 + row) * K + kt + cb * 8);
        }
        __syncthreads();
        FOR_M(G_DECL_A)
        FOR_M(G_DECL_B)
        FOR_MN(G_MFMA)
    }

#define G_OUTST(mi,ni) { _Pragma("unroll") \
        for (int r = 0; r < 4; r++) { \
            const int m = m0 + wy * 64 + (mi) * 16 + quad * 4 + r; \
            const int n = n0 + wx * 64 + (ni) * 16 + l15; \
            out[(size_t)m * 1024 + n] = c##mi##ni[r] + x[(size_t)m * 1024 + n]; } }
    FOR_MN(G_OUTST)
}

// ---------------------------------------------------------------------------
__global__ __launch_bounds__(256) void attn_mfma(
    const unsigned short* __restrict__ qb, const unsigned short* __restrict__ kb,
    const unsigned short* __restrict__ vT, unsigned short* __restrict__ zb)
{
    __shared__ unsigned short Qs[128 * 72];
    __shared__ unsigned short Ks[64 * 72];
    __shared__ unsigned short Vs[64 * 72];
    __shared__ unsigned short Pm[128 * 72];
    const int tid = threadIdx.x;
    const int qti = 15 - blockIdx.x;          // big tiles first
    const int bh = blockIdx.y;
    const int b = bh >> 4, h = bh & 15;
    const int lane = tid & 63, wq = tid >> 6;
    const int l15 = lane & 15, quad = lane >> 4;
    const size_t tokbase = (size_t)b * 2048;

#pragma unroll
    for (int j = 0; j < 4; j++) {
        int u = tid + j * 256;
        int row = u >> 3, cb = u & 7;
        *(bf16x8*)&Qs[row * 72 + cb * 8] =
            *(const bf16x8*)(qb + (tokbase + qti * 128 + row) * 1024 + h * 64 + cb * 8);
    }

#define A_DECL_Z(mi,kn) f32x4 z_##mi##kn = {0.f, 0.f, 0.f, 0.f};
    FOR_MN2(A_DECL_Z)

    const int nkt = 2 * qti + 2;
    for (int kt = 0; kt < nkt; kt++) {
        __syncthreads();
#pragma unroll
        for (int j = 0; j < 2; j++) {
            int u = tid + j * 256;
            int row = u >> 3, cb = u & 7;
            *(bf16x8*)&Ks[row * 72 + cb * 8] =
                *(const bf16x8*)(kb + (tokbase + kt * 64 + row) * 1024 + h * 64 + cb * 8);
            *(bf16x8*)&Vs[row * 72 + cb * 8] =
                *(const bf16x8*)(vT + ((size_t)bh * 64 + row) * 2048 + kt * 64 + cb * 8);
        }
        __syncthreads();

#define A_DECL_S(mi,kn) f32x4 s_##mi##kn = {0.f, 0.f, 0.f, 0.f};
        FOR_MN2(A_DECL_S)
#pragma unroll
        for (int ks = 0; ks < 2; ks++) {
#define A_DECL_AQ(mi) bf16x8 aq##mi = *(const bf16x8*)&Qs[(wq * 32 + (mi) * 16 + l15) * 72 + ks * 32 + quad * 8];
            A_DECL_AQ(0) A_DECL_AQ(1)
#define A_DECL_BK(kn) bf16x8 bb##kn = *(const bf16x8*)&Ks[((kn) * 16 + l15) * 72 + ks * 32 + quad * 8];
            FOR_M(A_DECL_BK)
#define A_SMFMA(mi,kn) s_##mi##kn = __builtin_amdgcn_mfma_f32_16x16x32_bf16(aq##mi, bb##kn, s_##mi##kn, 0, 0, 0);
            FOR_MN2(A_SMFMA)
        }

        const bool needmask = (kt >= 2 * qti);
#define A_PSTORE(mi,kn) { _Pragma("unroll") \
            for (int r = 0; r < 4; r++) { \
                const int qrow = qti * 128 + wq * 32 + (mi) * 16 + quad * 4 + r; \
                const int kcol = kt * 64 + (kn) * 16 + l15; \
                float sc = s_##mi##kn[r] * (1.0f / 64.0f); \
                float p = sc * sc; \
                if (needmask && kcol > qrow) p = 0.f; \
                Pm[(wq * 32 + (mi) * 16 + quad * 4 + r) * 72 + (kn) * 16 + l15] = f2bf(p); } }
        FOR_MN2(A_PSTORE)

#pragma unroll
        for (int ks = 0; ks < 2; ks++) {
#define A_DECL_AP(mi) bf16x8 ap##mi = *(const bf16x8*)&Pm[(wq * 32 + (mi) * 16 + l15) * 72 + ks * 32 + quad * 8];
            A_DECL_AP(0) A_DECL_AP(1)
#define A_DECL_BV(dn) bf16x8 bv##dn = *(const bf16x8*)&Vs[((dn) * 16 + l15) * 72 + ks * 32 + quad * 8];
            FOR_M(A_DECL_BV)
#define A_ZMFMA(mi,dn) z_##mi##dn = __builtin_amdgcn_mfma_f32_16x16x32_bf16(ap##mi, bv##dn, z_##mi##dn, 0, 0, 0);
            FOR_MN2(A_ZMFMA)
        }
    }

    // stage z into wave-private Pm rows, then 16B contiguous stores
#define A_ZST(mi,dn) { _Pragma("unroll") \
        for (int r = 0; r < 4; r++) \
            Pm[(wq * 32 + (mi) * 16 + quad * 4 + r) * 72 + (dn) * 16 + l15] = \
                f2bf(z_##mi##dn[r]); }
    FOR_MN2(A_ZST)
#pragma unroll
    for (int it = 0; it < 4; it++) {
        const int linear = it * 64 + lane;
        const int row = linear >> 3, cb = linear & 7;
        *(bf16x8*)(zb + (tokbase + qti * 128 + wq * 32 + row) * 1024 + h * 64 + cb * 8) =
            *(const bf16x8*)&Pm[(wq * 32 + row) * 72 + cb * 8];
    }
}

// ---------------------------------------------------------------------------
extern "C" void kernel_launch(void* const* d_in, const int* in_sizes, int n_in,
                              void* d_out, int out_size, void* d_ws, size_t ws_size,
                              hipStream_t stream)
{
    const float* x  = (const float*)d_in[0];
    const float* Wq = (const float*)d_in[1];
    const float* bq = (const float*)d_in[2];
    const float* Wk = (const float*)d_in[3];
    const float* bk = (const float*)d_in[4];
    const float* Wv = (const float*)d_in[5];
    const float* bv = (const float*)d_in[6];
    const float* Wo = (const float*)d_in[7];
    const float* nw = (const float*)d_in[8];
    float* out = (float*)d_out;

    const int D = 1024;
    const int M = in_sizes[0] / D;   // B*S = 4096

    unsigned short* xbb = (unsigned short*)d_ws;         // M*D
    unsigned short* Wqb = xbb + (size_t)M * D;           // D*D
    unsigned short* Wkb = Wqb + (size_t)D * D;
    unsigned short* Wvb = Wkb + (size_t)D * D;
    unsigned short* Wob = Wvb + (size_t)D * D;
    unsigned short* qbw = Wob + (size_t)D * D;           // M*D
    unsigned short* kbw = qbw + (size_t)M * D;
    unsigned short* vTw = kbw + (size_t)M * D;
    unsigned short* zbw = vTw + (size_t)M * D;

    const int nx4 = M * D / 4, nw4 = D * D / 4;
    cvt_bf16<<<(nx4 + 255) / 256, 256, 0, stream>>>(x, xbb, nx4);
    cvt_bf16<<<(nw4 + 255) / 256, 256, 0, stream>>>(Wq, Wqb, nw4);
    cvt_bf16<<<(nw4 + 255) / 256, 256, 0, stream>>>(Wk, Wkb, nw4);
    cvt_bf16<<<(nw4 + 255) / 256, 256, 0, stream>>>(Wv, Wvb, nw4);
    cvt_bf16<<<(nw4 + 255) / 256, 256, 0, stream>>>(Wo, Wob, nw4);

    gemm_qkv<<<dim3(D / 128, M / 128, 3), 256, 0, stream>>>(
        xbb, Wqb, Wkb, Wvb, bq, bk, bv, nw, qbw, kbw, vTw, M);

    attn_mfma<<<dim3(16, (M / 2048) * 16), 256, 0, stream>>>(qbw, kbw, vTw, zbw);

    gemm_out<<<dim3(D / 128, M / 128), 256, 0, stream>>>(zbw, Wob, x, out, M);
}

// Round 6
// 246.916 us; speedup vs baseline: 4.9349x; 1.0678x over previous
//
#include <hip/hip_runtime.h>
#include <math.h>

// QuadraticAttention on MI355X — round 6: global_load_lds (16B) staging.
// Round 5 fixed scratch spill (WRITE 1.46GB -> 24.6MB algorithmic). Now
// gemm_qkv is m93-class (318 TF, MfmaUtil 12.5%): VGPR-roundtrip staging is
// the bottleneck. Apply the m97 recipe: unpadded [128][32] (64B-row) LDS
// tiles filled by async global_load_lds width=16, 2-barrier K-loop.
// attn gets the same treatment with half-split [2][rows][32] tiles.
// cvt launches fused 5 -> 1.

typedef float  f32x4  __attribute__((ext_vector_type(4)));
typedef short  bf16x8 __attribute__((ext_vector_type(8)));
typedef float  vf4    __attribute__((ext_vector_type(4)));
typedef unsigned short u16x4 __attribute__((ext_vector_type(4)));

static __device__ __forceinline__ unsigned short f2bf(float f) {
    union { float f; unsigned int i; } c; c.f = f;
    unsigned int x = c.i;
    return (unsigned short)((x + 0x7fffu + ((x >> 16) & 1u)) >> 16);
}
static __device__ __forceinline__ f32x4 shfl_xor4(f32x4 v, int m) {
    f32x4 r;
    r[0] = __shfl_xor(v[0], m); r[1] = __shfl_xor(v[1], m);
    r[2] = __shfl_xor(v[2], m); r[3] = __shfl_xor(v[3], m);
    return r;
}
static __device__ __forceinline__ f32x4 rsq4(f32x4 v) {
    f32x4 r;
#pragma unroll
    for (int i = 0; i < 4; i++) r[i] = rsqrtf(v[i] * (1.0f / 64.0f) + 1.1920929e-07f);
    return r;
}
// async 16B/lane global -> LDS (wave-uniform LDS base + lane*16)
static __device__ __forceinline__ void cp16(const unsigned short* g, unsigned short* l) {
    __builtin_amdgcn_global_load_lds(
        (const __attribute__((address_space(1))) unsigned int*)g,
        (__attribute__((address_space(3))) unsigned int*)l, 16, 0, 0);
}

#define FOR_M(X)  X(0) X(1) X(2) X(3)
#define FOR_MN(X) X(0,0) X(0,1) X(0,2) X(0,3) X(1,0) X(1,1) X(1,2) X(1,3) \
                  X(2,0) X(2,1) X(2,2) X(2,3) X(3,0) X(3,1) X(3,2) X(3,3)
#define FOR_MN2(X) X(0,0) X(0,1) X(0,2) X(0,3) X(1,0) X(1,1) X(1,2) X(1,3)

// ---------------------------------------------------------------------------
// fused fp32->bf16 conversion for x + 4 weight matrices (1 launch)
// ---------------------------------------------------------------------------
__global__ __launch_bounds__(256) void cvt_all(
    const float* __restrict__ x,  const float* __restrict__ Wq,
    const float* __restrict__ Wk, const float* __restrict__ Wv,
    const float* __restrict__ Wo,
    unsigned short* __restrict__ xb,  unsigned short* __restrict__ Wqb,
    unsigned short* __restrict__ Wkb, unsigned short* __restrict__ Wvb,
    unsigned short* __restrict__ Wob, int nx4, int nw4)
{
    int i = blockIdx.x * 256 + threadIdx.x;
    const float* s; unsigned short* d; int li;
    if (i < nx4) { s = x; d = xb; li = i; }
    else {
        int idx = i - nx4;
        int r = idx / nw4; li = idx - r * nw4;
        if (r >= 4) return;
        s = (r == 0) ? Wq : (r == 1) ? Wk : (r == 2) ? Wv : Wo;
        d = (r == 0) ? Wqb : (r == 1) ? Wkb : (r == 2) ? Wvb : Wob;
    }
    vf4 v = *(const vf4*)(s + (size_t)li * 4);
    u16x4 o;
#pragma unroll
    for (int j = 0; j < 4; j++) o[j] = f2bf(v[j]);
    *(u16x4*)(d + (size_t)li * 4) = o;
}

// ---------------------------------------------------------------------------
#define SS 136   // epilogue stage row stride (elems)

// GEMM-core macros; LDS tiles are unpadded [128][32] (row = 64 B)
#define G_DECL_ACC(mi,ni) f32x4 c##mi##ni = {0.f, 0.f, 0.f, 0.f};
#define G_DECL_A(mi) bf16x8 a##mi = *(const bf16x8*)&As[(wy * 64 + (mi) * 16 + l15) * 32 + quad * 8];
#define G_DECL_B(ni) bf16x8 b##ni = *(const bf16x8*)&Ws[(wx * 64 + (ni) * 16 + l15) * 32 + quad * 8];
#define G_MFMA(mi,ni) c##mi##ni = __builtin_amdgcn_mfma_f32_16x16x32_bf16(a##mi, b##ni, c##mi##ni, 0, 0, 0);

__global__ __launch_bounds__(256) void gemm_qkv(
    const unsigned short* __restrict__ xb,
    const unsigned short* __restrict__ Wqb,
    const unsigned short* __restrict__ Wkb,
    const unsigned short* __restrict__ Wvb,
    const float* __restrict__ bqf, const float* __restrict__ bkf, const float* __restrict__ bvf,
    const float* __restrict__ nwp,
    unsigned short* __restrict__ qb, unsigned short* __restrict__ kb,
    unsigned short* __restrict__ vT, int M)
{
    const int K = 1024;
    __shared__ unsigned short smem[128 * SS];   // 34816 B; [As|Ws] then stage
    unsigned short* As = smem;                  // 128*32 = 4096 elems
    unsigned short* Ws = smem + 4096;
    const int tid = threadIdx.x;
    const int z = blockIdx.z;
    const unsigned short* Wb = (z == 0) ? Wqb : (z == 1) ? Wkb : Wvb;
    const float* bias = (z == 0) ? bqf : (z == 1) ? bkf : bvf;
    const int n0 = blockIdx.x * 128;
    const int m0 = blockIdx.y * 128;
    const int lane = tid & 63, wid = tid >> 6;
    const int wy = wid >> 1, wx = wid & 1;
    const int l15 = lane & 15, quad = lane >> 4;
    const int r16 = lane >> 2;          // staging: row within 16-row chunk
    const int c8  = (lane & 3) * 8;     // staging: elem offset within row

    FOR_MN(G_DECL_ACC)

    for (int kt = 0; kt < K; kt += 32) {
        __syncthreads();
#pragma unroll
        for (int j = 0; j < 2; j++) {
            const int ch = wid * 2 + j;               // 0..7, 16 rows each
            const int row = ch * 16 + r16;
            cp16(xb + (size_t)(m0 + row) * K + kt + c8, &As[ch * 512]);
            cp16(Wb + (size_t)(n0 + row) * K + kt + c8, &Ws[ch * 512]);
        }
        __syncthreads();
        FOR_M(G_DECL_A)
        FOR_M(G_DECL_B)
        FOR_MN(G_MFMA)
    }
    __syncthreads();   // MFMA LDS reads done before smem reused as stage

    // ---- epilogue ----
#define G_DECL_BIAS(ni) float bs##ni = bias[n0 + wx * 64 + (ni) * 16 + l15]; \
                        float nww##ni = nwp[(ni) * 16 + l15];
    FOR_M(G_DECL_BIAS)
#define G_ADD_BIAS(mi,ni) c##mi##ni = c##mi##ni + bs##ni;
    FOR_MN(G_ADD_BIAS)

    if (z < 2) {
#define G_SUMSQ(mi) f32x4 s2_##mi = c##mi##0 * c##mi##0 + c##mi##1 * c##mi##1 + \
                                    c##mi##2 * c##mi##2 + c##mi##3 * c##mi##3;
        FOR_M(G_SUMSQ)
#define G_RED(mi) s2_##mi = s2_##mi + shfl_xor4(s2_##mi, 1); \
                  s2_##mi = s2_##mi + shfl_xor4(s2_##mi, 2); \
                  s2_##mi = s2_##mi + shfl_xor4(s2_##mi, 4); \
                  s2_##mi = s2_##mi + shfl_xor4(s2_##mi, 8); \
                  s2_##mi = rsq4(s2_##mi);
        FOR_M(G_RED)

        const float lf0 = expf(-(float)l15 * 0.28782313662425572f);          // ln(1e4)/32
        const float lf1 = expf(-(float)(l15 + 16) * 0.28782313662425572f);

#define G_ROPE_ONE(mi,ni,CS,SN) { \
            float vn = c##mi##ni[r] * s2v[r] * nww##ni; \
            float pt = __shfl_xor(vn, 1); \
            float rot = (lane & 1) ? pt : -pt; \
            smem[mrow * SS + wx * 64 + (ni) * 16 + l15] = f2bf(vn * (CS) + rot * (SN)); }
#define G_ROPE_MI(mi) { f32x4 s2v = s2_##mi; \
            _Pragma("unroll") \
            for (int r = 0; r < 4; r++) { \
                const int mrow = wy * 64 + (mi) * 16 + quad * 4 + r; \
                const float t = (float)((m0 + mrow) & 2047); \
                const float a0 = t * lf0, a1 = t * lf1; \
                const float cs0 = cosf(a0), sn0 = sinf(a0); \
                const float cs1 = cosf(a1), sn1 = sinf(a1); \
                G_ROPE_ONE(mi,0,cs0,sn0) G_ROPE_ONE(mi,1,cs1,sn1) \
                G_ROPE_ONE(mi,2,cs0,sn0) G_ROPE_ONE(mi,3,cs1,sn1) } }
        FOR_M(G_ROPE_MI)

        __syncthreads();
        unsigned short* dst = (z == 0) ? qb : kb;
#pragma unroll
        for (int it = 0; it < 8; it++) {
            const int linear = tid + it * 256;
            const int row = linear >> 4, cb = linear & 15;
            *(bf16x8*)(dst + (size_t)(m0 + row) * 1024 + n0 + cb * 8) =
                *(const bf16x8*)&smem[row * SS + cb * 8];
        }
    } else {
#define G_VST(mi,ni) { _Pragma("unroll") \
            for (int r = 0; r < 4; r++) { \
                const int mrow = wy * 64 + (mi) * 16 + quad * 4 + r; \
                smem[(wx * 64 + (ni) * 16 + l15) * SS + mrow] = f2bf(c##mi##ni[r]); } }
        FOR_MN(G_VST)
        __syncthreads();
        const int b = m0 >> 11, tok0 = m0 & 2047;
#pragma unroll
        for (int it = 0; it < 8; it++) {
            const int linear = tid + it * 256;
            const int rowd = linear >> 4, cb = linear & 15;
            const int head_g = (n0 >> 6) + (rowd >> 6);
            const int d = rowd & 63;
            *(bf16x8*)(vT + (((size_t)b * 16 + head_g) * 64 + d) * 2048 + tok0 + cb * 8) =
                *(const bf16x8*)&smem[rowd * SS + cb * 8];
        }
    }
}

// ---------------------------------------------------------------------------
__global__ __launch_bounds__(256) void gemm_out(
    const unsigned short* __restrict__ zb,
    const unsigned short* __restrict__ Wob,
    const float* __restrict__ x, float* __restrict__ out, int M)
{
    const int K = 1024;
    __shared__ unsigned short As[4096];
    __shared__ unsigned short Ws[4096];
    const int tid = threadIdx.x;
    const int n0 = blockIdx.x * 128;
    const int m0 = blockIdx.y * 128;
    const int lane = tid & 63, wid = tid >> 6;
    const int wy = wid >> 1, wx = wid & 1;
    const int l15 = lane & 15, quad = lane >> 4;
    const int r16 = lane >> 2;
    const int c8  = (lane & 3) * 8;

    FOR_MN(G_DECL_ACC)

    for (int kt = 0; kt < K; kt += 32) {
        __syncthreads();
#pragma unroll
        for (int j = 0; j < 2; j++) {
            const int ch = wid * 2 + j;
            const int row = ch * 16 + r16;
            cp16(zb + (size_t)(m0 + row) * K + kt + c8, &As[ch * 512]);
            cp16(Wob + (size_t)(n0 + row) * K + kt + c8, &Ws[ch * 512]);
        }
        __syncthreads();
        FOR_M(G_DECL_A)
        FOR_M(G_DECL_B)
        FOR_MN(G_MFMA)
    }

#define G_OUTST(mi,ni) { _Pragma("unroll") \
        for (int r = 0; r < 4; r++) { \
            const int m = m0 + wy * 64 + (mi) * 16 + quad * 4 + r; \
            const int n = n0 + wx * 64 + (ni) * 16 + l15; \
            out[(size_t)m * 1024 + n] = c##mi##ni[r] + x[(size_t)m * 1024 + n]; } }
    FOR_MN(G_OUTST)
}

// ---------------------------------------------------------------------------
// Causal quadratic attention. Tiles staged via global_load_lds into
// half-split layouts [2 halves][rows][32] (64B rows). Pm stays padded (72).
// ---------------------------------------------------------------------------
__global__ __launch_bounds__(256) void attn_mfma(
    const unsigned short* __restrict__ qb, const unsigned short* __restrict__ kb,
    const unsigned short* __restrict__ vT, unsigned short* __restrict__ zb)
{
    __shared__ unsigned short Qs[8192];       // [2][128][32]
    __shared__ unsigned short Ks[4096];       // [2][64][32]
    __shared__ unsigned short Vs[4096];       // [2][64][32] (rows = d)
    __shared__ unsigned short Pm[128 * 72];
    const int tid = threadIdx.x;
    const int qti = 15 - blockIdx.x;          // big tiles first
    const int bh = blockIdx.y;
    const int b = bh >> 4, h = bh & 15;
    const int lane = tid & 63, wq = tid >> 6;
    const int l15 = lane & 15, quad = lane >> 4;
    const int r16 = lane >> 2;
    const int c8  = (lane & 3) * 8;
    const size_t tokbase = (size_t)b * 2048;

    // Q: 16 chunks of 16 rows; chunk ch: half = ch>>3, local row group ch&7
#pragma unroll
    for (int j = 0; j < 4; j++) {
        const int ch = wq * 4 + j;
        const int half = ch >> 3;
        const int row = (ch & 7) * 16 + r16;
        cp16(qb + (tokbase + qti * 128 + row) * 1024 + h * 64 + half * 32 + c8,
             &Qs[ch * 512]);
    }

#define A_DECL_Z(mi,kn) f32x4 z_##mi##kn = {0.f, 0.f, 0.f, 0.f};
    FOR_MN2(A_DECL_Z)

    const int nkt = 2 * qti + 2;
    for (int kt = 0; kt < nkt; kt++) {
        __syncthreads();
#pragma unroll
        for (int j = 0; j < 2; j++) {
            const int ch = wq * 2 + j;            // 0..7
            const int half = ch >> 2;
            const int row = (ch & 3) * 16 + r16;
            cp16(kb + (tokbase + kt * 64 + row) * 1024 + h * 64 + half * 32 + c8,
                 &Ks[ch * 512]);
            cp16(vT + ((size_t)bh * 64 + row) * 2048 + kt * 64 + half * 32 + c8,
                 &Vs[ch * 512]);
        }
        __syncthreads();

#define A_DECL_S(mi,kn) f32x4 s_##mi##kn = {0.f, 0.f, 0.f, 0.f};
        FOR_MN2(A_DECL_S)
#pragma unroll
        for (int ks = 0; ks < 2; ks++) {
#define A_DECL_AQ(mi) bf16x8 aq##mi = *(const bf16x8*)&Qs[ks * 4096 + (wq * 32 + (mi) * 16 + l15) * 32 + quad * 8];
            A_DECL_AQ(0) A_DECL_AQ(1)
#define A_DECL_BK(kn) bf16x8 bb##kn = *(const bf16x8*)&Ks[ks * 2048 + ((kn) * 16 + l15) * 32 + quad * 8];
            FOR_M(A_DECL_BK)
#define A_SMFMA(mi,kn) s_##mi##kn = __builtin_amdgcn_mfma_f32_16x16x32_bf16(aq##mi, bb##kn, s_##mi##kn, 0, 0, 0);
            FOR_MN2(A_SMFMA)
        }

        const bool needmask = (kt >= 2 * qti);
#define A_PSTORE(mi,kn) { _Pragma("unroll") \
            for (int r = 0; r < 4; r++) { \
                const int qrow = qti * 128 + wq * 32 + (mi) * 16 + quad * 4 + r; \
                const int kcol = kt * 64 + (kn) * 16 + l15; \
                float sc = s_##mi##kn[r] * (1.0f / 64.0f); \
                float p = sc * sc; \
                if (needmask && kcol > qrow) p = 0.f; \
                Pm[(wq * 32 + (mi) * 16 + quad * 4 + r) * 72 + (kn) * 16 + l15] = f2bf(p); } }
        FOR_MN2(A_PSTORE)

#pragma unroll
        for (int ks = 0; ks < 2; ks++) {
#define A_DECL_AP(mi) bf16x8 ap##mi = *(const bf16x8*)&Pm[(wq * 32 + (mi) * 16 + l15) * 72 + ks * 32 + quad * 8];
            A_DECL_AP(0) A_DECL_AP(1)
#define A_DECL_BV(dn) bf16x8 bv##dn = *(const bf16x8*)&Vs[ks * 2048 + ((dn) * 16 + l15) * 32 + quad * 8];
            FOR_M(A_DECL_BV)
#define A_ZMFMA(mi,dn) z_##mi##dn = __builtin_amdgcn_mfma_f32_16x16x32_bf16(ap##mi, bv##dn, z_##mi##dn, 0, 0, 0);
            FOR_MN2(A_ZMFMA)
        }
    }

    // stage z into wave-private Pm rows, then 16B contiguous stores
#define A_ZST(mi,dn) { _Pragma("unroll") \
        for (int r = 0; r < 4; r++) \
            Pm[(wq * 32 + (mi) * 16 + quad * 4 + r) * 72 + (dn) * 16 + l15] = \
                f2bf(z_##mi##dn[r]); }
    FOR_MN2(A_ZST)
#pragma unroll
    for (int it = 0; it < 4; it++) {
        const int linear = it * 64 + lane;
        const int row = linear >> 3, cb = linear & 7;
        *(bf16x8*)(zb + (tokbase + qti * 128 + wq * 32 + row) * 1024 + h * 64 + cb * 8) =
            *(const bf16x8*)&Pm[(wq * 32 + row) * 72 + cb * 8];
    }
}

// ---------------------------------------------------------------------------
extern "C" void kernel_launch(void* const* d_in, const int* in_sizes, int n_in,
                              void* d_out, int out_size, void* d_ws, size_t ws_size,
                              hipStream_t stream)
{
    const float* x  = (const float*)d_in[0];
    const float* Wq = (const float*)d_in[1];
    const float* bq = (const float*)d_in[2];
    const float* Wk = (const float*)d_in[3];
    const float* bk = (const float*)d_in[4];
    const float* Wv = (const float*)d_in[5];
    const float* bv = (const float*)d_in[6];
    const float* Wo = (const float*)d_in[7];
    const float* nw = (const float*)d_in[8];
    float* out = (float*)d_out;

    const int D = 1024;
    const int M = in_sizes[0] / D;   // B*S = 4096

    unsigned short* xbb = (unsigned short*)d_ws;         // M*D
    unsigned short* Wqb = xbb + (size_t)M * D;           // D*D
    unsigned short* Wkb = Wqb + (size_t)D * D;
    unsigned short* Wvb = Wkb + (size_t)D * D;
    unsigned short* Wob = Wvb + (size_t)D * D;
    unsigned short* qbw = Wob + (size_t)D * D;           // M*D
    unsigned short* kbw = qbw + (size_t)M * D;
    unsigned short* vTw = kbw + (size_t)M * D;
    unsigned short* zbw = vTw + (size_t)M * D;

    const int nx4 = M * D / 4, nw4 = D * D / 4;
    const int ncvt = nx4 + 4 * nw4;
    cvt_all<<<(ncvt + 255) / 256, 256, 0, stream>>>(
        x, Wq, Wk, Wv, Wo, xbb, Wqb, Wkb, Wvb, Wob, nx4, nw4);

    gemm_qkv<<<dim3(D / 128, M / 128, 3), 256, 0, stream>>>(
        xbb, Wqb, Wkb, Wvb, bq, bk, bv, nw, qbw, kbw, vTw, M);

    attn_mfma<<<dim3(16, (M / 2048) * 16), 256, 0, stream>>>(qbw, kbw, vTw, zbw);

    gemm_out<<<dim3(D / 128, M / 128), 256, 0, stream>>>(zbw, Wob, x, out, M);
}

// Round 7
// 242.592 us; speedup vs baseline: 5.0229x; 1.0178x over previous
//
#include <hip/hip_runtime.h>
#include <math.h>

// QuadraticAttention on MI355X — round 7: attention load balance + occupancy.
// Round 6: attn_mfma 73us, MfmaUtil 9.5%, Occupancy 11% — 512 blocks (2/CU),
// causal imbalance 2..32 k-iters/block. Now: 64-row q-tiles -> 1024 blocks,
// 33KB LDS -> 4 blocks/CU, critical path halved. GEMMs/cvt unchanged (m97
// global_load_lds staging, named-register accumulators).

typedef float  f32x4  __attribute__((ext_vector_type(4)));
typedef short  bf16x8 __attribute__((ext_vector_type(8)));
typedef float  vf4    __attribute__((ext_vector_type(4)));
typedef unsigned short u16x4 __attribute__((ext_vector_type(4)));

static __device__ __forceinline__ unsigned short f2bf(float f) {
    union { float f; unsigned int i; } c; c.f = f;
    unsigned int x = c.i;
    return (unsigned short)((x + 0x7fffu + ((x >> 16) & 1u)) >> 16);
}
static __device__ __forceinline__ f32x4 shfl_xor4(f32x4 v, int m) {
    f32x4 r;
    r[0] = __shfl_xor(v[0], m); r[1] = __shfl_xor(v[1], m);
    r[2] = __shfl_xor(v[2], m); r[3] = __shfl_xor(v[3], m);
    return r;
}
static __device__ __forceinline__ f32x4 rsq4(f32x4 v) {
    f32x4 r;
#pragma unroll
    for (int i = 0; i < 4; i++) r[i] = rsqrtf(v[i] * (1.0f / 64.0f) + 1.1920929e-07f);
    return r;
}
// async 16B/lane global -> LDS (wave-uniform LDS base + lane*16)
static __device__ __forceinline__ void cp16(const unsigned short* g, unsigned short* l) {
    __builtin_amdgcn_global_load_lds(
        (const __attribute__((address_space(1))) unsigned int*)g,
        (__attribute__((address_space(3))) unsigned int*)l, 16, 0, 0);
}

#define FOR_M(X)  X(0) X(1) X(2) X(3)
#define FOR_MN(X) X(0,0) X(0,1) X(0,2) X(0,3) X(1,0) X(1,1) X(1,2) X(1,3) \
                  X(2,0) X(2,1) X(2,2) X(2,3) X(3,0) X(3,1) X(3,2) X(3,3)

// ---------------------------------------------------------------------------
// fused fp32->bf16 conversion for x + 4 weight matrices (1 launch)
// ---------------------------------------------------------------------------
__global__ __launch_bounds__(256) void cvt_all(
    const float* __restrict__ x,  const float* __restrict__ Wq,
    const float* __restrict__ Wk, const float* __restrict__ Wv,
    const float* __restrict__ Wo,
    unsigned short* __restrict__ xb,  unsigned short* __restrict__ Wqb,
    unsigned short* __restrict__ Wkb, unsigned short* __restrict__ Wvb,
    unsigned short* __restrict__ Wob, int nx4, int nw4)
{
    int i = blockIdx.x * 256 + threadIdx.x;
    const float* s; unsigned short* d; int li;
    if (i < nx4) { s = x; d = xb; li = i; }
    else {
        int idx = i - nx4;
        int r = idx / nw4; li = idx - r * nw4;
        if (r >= 4) return;
        s = (r == 0) ? Wq : (r == 1) ? Wk : (r == 2) ? Wv : Wo;
        d = (r == 0) ? Wqb : (r == 1) ? Wkb : (r == 2) ? Wvb : Wob;
    }
    vf4 v = *(const vf4*)(s + (size_t)li * 4);
    u16x4 o;
#pragma unroll
    for (int j = 0; j < 4; j++) o[j] = f2bf(v[j]);
    *(u16x4*)(d + (size_t)li * 4) = o;
}

// ---------------------------------------------------------------------------
#define SS 136   // epilogue stage row stride (elems)

// GEMM-core macros; LDS tiles are unpadded [128][32] (row = 64 B)
#define G_DECL_ACC(mi,ni) f32x4 c##mi##ni = {0.f, 0.f, 0.f, 0.f};
#define G_DECL_A(mi) bf16x8 a##mi = *(const bf16x8*)&As[(wy * 64 + (mi) * 16 + l15) * 32 + quad * 8];
#define G_DECL_B(ni) bf16x8 b##ni = *(const bf16x8*)&Ws[(wx * 64 + (ni) * 16 + l15) * 32 + quad * 8];
#define G_MFMA(mi,ni) c##mi##ni = __builtin_amdgcn_mfma_f32_16x16x32_bf16(a##mi, b##ni, c##mi##ni, 0, 0, 0);

__global__ __launch_bounds__(256) void gemm_qkv(
    const unsigned short* __restrict__ xb,
    const unsigned short* __restrict__ Wqb,
    const unsigned short* __restrict__ Wkb,
    const unsigned short* __restrict__ Wvb,
    const float* __restrict__ bqf, const float* __restrict__ bkf, const float* __restrict__ bvf,
    const float* __restrict__ nwp,
    unsigned short* __restrict__ qb, unsigned short* __restrict__ kb,
    unsigned short* __restrict__ vT, int M)
{
    const int K = 1024;
    __shared__ unsigned short smem[128 * SS];   // 34816 B; [As|Ws] then stage
    unsigned short* As = smem;                  // 128*32 = 4096 elems
    unsigned short* Ws = smem + 4096;
    const int tid = threadIdx.x;
    const int z = blockIdx.z;
    const unsigned short* Wb = (z == 0) ? Wqb : (z == 1) ? Wkb : Wvb;
    const float* bias = (z == 0) ? bqf : (z == 1) ? bkf : bvf;
    const int n0 = blockIdx.x * 128;
    const int m0 = blockIdx.y * 128;
    const int lane = tid & 63, wid = tid >> 6;
    const int wy = wid >> 1, wx = wid & 1;
    const int l15 = lane & 15, quad = lane >> 4;
    const int r16 = lane >> 2;          // staging: row within 16-row chunk
    const int c8  = (lane & 3) * 8;     // staging: elem offset within row

    FOR_MN(G_DECL_ACC)

    for (int kt = 0; kt < K; kt += 32) {
        __syncthreads();
#pragma unroll
        for (int j = 0; j < 2; j++) {
            const int ch = wid * 2 + j;               // 0..7, 16 rows each
            const int row = ch * 16 + r16;
            cp16(xb + (size_t)(m0 + row) * K + kt + c8, &As[ch * 512]);
            cp16(Wb + (size_t)(n0 + row) * K + kt + c8, &Ws[ch * 512]);
        }
        __syncthreads();
        FOR_M(G_DECL_A)
        FOR_M(G_DECL_B)
        FOR_MN(G_MFMA)
    }
    __syncthreads();   // MFMA LDS reads done before smem reused as stage

    // ---- epilogue ----
#define G_DECL_BIAS(ni) float bs##ni = bias[n0 + wx * 64 + (ni) * 16 + l15]; \
                        float nww##ni = nwp[(ni) * 16 + l15];
    FOR_M(G_DECL_BIAS)
#define G_ADD_BIAS(mi,ni) c##mi##ni = c##mi##ni + bs##ni;
    FOR_MN(G_ADD_BIAS)

    if (z < 2) {
#define G_SUMSQ(mi) f32x4 s2_##mi = c##mi##0 * c##mi##0 + c##mi##1 * c##mi##1 + \
                                    c##mi##2 * c##mi##2 + c##mi##3 * c##mi##3;
        FOR_M(G_SUMSQ)
#define G_RED(mi) s2_##mi = s2_##mi + shfl_xor4(s2_##mi, 1); \
                  s2_##mi = s2_##mi + shfl_xor4(s2_##mi, 2); \
                  s2_##mi = s2_##mi + shfl_xor4(s2_##mi, 4); \
                  s2_##mi = s2_##mi + shfl_xor4(s2_##mi, 8); \
                  s2_##mi = rsq4(s2_##mi);
        FOR_M(G_RED)

        const float lf0 = expf(-(float)l15 * 0.28782313662425572f);          // ln(1e4)/32
        const float lf1 = expf(-(float)(l15 + 16) * 0.28782313662425572f);

#define G_ROPE_ONE(mi,ni,CS,SN) { \
            float vn = c##mi##ni[r] * s2v[r] * nww##ni; \
            float pt = __shfl_xor(vn, 1); \
            float rot = (lane & 1) ? pt : -pt; \
            smem[mrow * SS + wx * 64 + (ni) * 16 + l15] = f2bf(vn * (CS) + rot * (SN)); }
#define G_ROPE_MI(mi) { f32x4 s2v = s2_##mi; \
            _Pragma("unroll") \
            for (int r = 0; r < 4; r++) { \
                const int mrow = wy * 64 + (mi) * 16 + quad * 4 + r; \
                const float t = (float)((m0 + mrow) & 2047); \
                const float a0 = t * lf0, a1 = t * lf1; \
                const float cs0 = cosf(a0), sn0 = sinf(a0); \
                const float cs1 = cosf(a1), sn1 = sinf(a1); \
                G_ROPE_ONE(mi,0,cs0,sn0) G_ROPE_ONE(mi,1,cs1,sn1) \
                G_ROPE_ONE(mi,2,cs0,sn0) G_ROPE_ONE(mi,3,cs1,sn1) } }
        FOR_M(G_ROPE_MI)

        __syncthreads();
        unsigned short* dst = (z == 0) ? qb : kb;
#pragma unroll
        for (int it = 0; it < 8; it++) {
            const int linear = tid + it * 256;
            const int row = linear >> 4, cb = linear & 15;
            *(bf16x8*)(dst + (size_t)(m0 + row) * 1024 + n0 + cb * 8) =
                *(const bf16x8*)&smem[row * SS + cb * 8];
        }
    } else {
#define G_VST(mi,ni) { _Pragma("unroll") \
            for (int r = 0; r < 4; r++) { \
                const int mrow = wy * 64 + (mi) * 16 + quad * 4 + r; \
                smem[(wx * 64 + (ni) * 16 + l15) * SS + mrow] = f2bf(c##mi##ni[r]); } }
        FOR_MN(G_VST)
        __syncthreads();
        const int b = m0 >> 11, tok0 = m0 & 2047;
#pragma unroll
        for (int it = 0; it < 8; it++) {
            const int linear = tid + it * 256;
            const int rowd = linear >> 4, cb = linear & 15;
            const int head_g = (n0 >> 6) + (rowd >> 6);
            const int d = rowd & 63;
            *(bf16x8*)(vT + (((size_t)b * 16 + head_g) * 64 + d) * 2048 + tok0 + cb * 8) =
                *(const bf16x8*)&smem[rowd * SS + cb * 8];
        }
    }
}

// ---------------------------------------------------------------------------
__global__ __launch_bounds__(256) void gemm_out(
    const unsigned short* __restrict__ zb,
    const unsigned short* __restrict__ Wob,
    const float* __restrict__ x, float* __restrict__ out, int M)
{
    const int K = 1024;
    __shared__ unsigned short As[4096];
    __shared__ unsigned short Ws[4096];
    const int tid = threadIdx.x;
    const int n0 = blockIdx.x * 128;
    const int m0 = blockIdx.y * 128;
    const int lane = tid & 63, wid = tid >> 6;
    const int wy = wid >> 1, wx = wid & 1;
    const int l15 = lane & 15, quad = lane >> 4;
    const int r16 = lane >> 2;
    const int c8  = (lane & 3) * 8;

    FOR_MN(G_DECL_ACC)

    for (int kt = 0; kt < K; kt += 32) {
        __syncthreads();
#pragma unroll
        for (int j = 0; j < 2; j++) {
            const int ch = wid * 2 + j;
            const int row = ch * 16 + r16;
            cp16(zb + (size_t)(m0 + row) * K + kt + c8, &As[ch * 512]);
            cp16(Wob + (size_t)(n0 + row) * K + kt + c8, &Ws[ch * 512]);
        }
        __syncthreads();
        FOR_M(G_DECL_A)
        FOR_M(G_DECL_B)
        FOR_MN(G_MFMA)
    }

#define G_OUTST(mi,ni) { _Pragma("unroll") \
        for (int r = 0; r < 4; r++) { \
            const int m = m0 + wy * 64 + (mi) * 16 + quad * 4 + r; \
            const int n = n0 + wx * 64 + (ni) * 16 + l15; \
            out[(size_t)m * 1024 + n] = c##mi##ni[r] + x[(size_t)m * 1024 + n]; } }
    FOR_MN(G_OUTST)
}

// ---------------------------------------------------------------------------
// Causal quadratic attention, rebalanced: one block = 64 q-rows of one (b,h),
// grid (32 qt, 32 bh) = 1024 blocks (~4/CU), big q-tiles launched first.
// Wave w owns q-rows [qt*64 + w*16, +16). Tiles staged via global_load_lds
// into half-split [2][64][32] layouts (64B rows). P roundtrip via per-wave
// Pm rows (stride 72), no barrier needed.
// ---------------------------------------------------------------------------
__global__ __launch_bounds__(256) void attn_mfma(
    const unsigned short* __restrict__ qb, const unsigned short* __restrict__ kb,
    const unsigned short* __restrict__ vT, unsigned short* __restrict__ zb)
{
    __shared__ unsigned short Qs[4096];       // [2][64][32]
    __shared__ unsigned short Ks[4096];       // [2][64][32]
    __shared__ unsigned short Vs[4096];       // [2][64][32] (rows = d)
    __shared__ unsigned short Pm[64 * 72];
    const int tid = threadIdx.x;
    const int qt = 31 - blockIdx.x;           // 0..31, big tiles first
    const int bh = blockIdx.y;
    const int b = bh >> 4, h = bh & 15;
    const int lane = tid & 63, wq = tid >> 6;
    const int l15 = lane & 15, quad = lane >> 4;
    const int r16 = lane >> 2;
    const int c8  = (lane & 3) * 8;
    const size_t tokbase = (size_t)b * 2048;
    const int q0 = qt * 64;

    // Q: 8 cp16 chunks of 16 rows; chunk ch: half = ch>>2, rowgrp = ch&3
#pragma unroll
    for (int j = 0; j < 2; j++) {
        const int ch = wq * 2 + j;
        const int half = ch >> 2;
        const int row = (ch & 3) * 16 + r16;
        cp16(qb + (tokbase + q0 + row) * 1024 + h * 64 + half * 32 + c8, &Qs[ch * 512]);
    }

#define A_DECL_Z(n) f32x4 z_##n = {0.f, 0.f, 0.f, 0.f};
    FOR_M(A_DECL_Z)

    const int nkt = qt + 1;
    for (int kt = 0; kt < nkt; kt++) {
        __syncthreads();   // prev-iter LDS readers done; also drains cp16 vmcnt
#pragma unroll
        for (int j = 0; j < 2; j++) {
            const int ch = wq * 2 + j;
            const int half = ch >> 2;
            const int row = (ch & 3) * 16 + r16;
            cp16(kb + (tokbase + kt * 64 + row) * 1024 + h * 64 + half * 32 + c8,
                 &Ks[ch * 512]);
            cp16(vT + ((size_t)bh * 64 + row) * 2048 + kt * 64 + half * 32 + c8,
                 &Vs[ch * 512]);
        }
        __syncthreads();

        // S = Q K^T : wave computes 16 q-rows x 64 k-cols
#define A_DECL_S(n) f32x4 s_##n = {0.f, 0.f, 0.f, 0.f};
        FOR_M(A_DECL_S)
#pragma unroll
        for (int ks = 0; ks < 2; ks++) {
            bf16x8 aq = *(const bf16x8*)&Qs[ks * 2048 + (wq * 16 + l15) * 32 + quad * 8];
#define A_DECL_BK(n) bf16x8 bb##n = *(const bf16x8*)&Ks[ks * 2048 + ((n) * 16 + l15) * 32 + quad * 8];
            FOR_M(A_DECL_BK)
#define A_SMFMA(n) s_##n = __builtin_amdgcn_mfma_f32_16x16x32_bf16(aq, bb##n, s_##n, 0, 0, 0);
            FOR_M(A_SMFMA)
        }

        // P = (S/64)^2, causal mask only on the diagonal tile
        const bool needmask = (kt == qt);
#define A_PSTORE(n) { _Pragma("unroll") \
            for (int r = 0; r < 4; r++) { \
                const int qrow = q0 + wq * 16 + quad * 4 + r; \
                const int kcol = kt * 64 + (n) * 16 + l15; \
                float sc = s_##n[r] * (1.0f / 64.0f); \
                float p = sc * sc; \
                if (needmask && kcol > qrow) p = 0.f; \
                Pm[(wq * 16 + quad * 4 + r) * 72 + (n) * 16 + l15] = f2bf(p); } }
        FOR_M(A_PSTORE)

        // Z += P @ V  (A = wave's Pm rows; B from Vt tile)
#pragma unroll
        for (int ks = 0; ks < 2; ks++) {
            bf16x8 ap = *(const bf16x8*)&Pm[(wq * 16 + l15) * 72 + ks * 32 + quad * 8];
#define A_DECL_BV(n) bf16x8 bv##n = *(const bf16x8*)&Vs[ks * 2048 + ((n) * 16 + l15) * 32 + quad * 8];
            FOR_M(A_DECL_BV)
#define A_ZMFMA(n) z_##n = __builtin_amdgcn_mfma_f32_16x16x32_bf16(ap, bv##n, z_##n, 0, 0, 0);
            FOR_M(A_ZMFMA)
        }
    }

    // stage z into wave-private Pm rows, then 16B contiguous stores
#define A_ZST(n) { _Pragma("unroll") \
        for (int r = 0; r < 4; r++) \
            Pm[(wq * 16 + quad * 4 + r) * 72 + (n) * 16 + l15] = f2bf(z_##n[r]); }
    FOR_M(A_ZST)
#pragma unroll
    for (int it = 0; it < 2; it++) {
        const int linear = it * 64 + lane;
        const int row = linear >> 3, cb = linear & 7;   // 16 rows x 8 segs
        *(bf16x8*)(zb + (tokbase + q0 + wq * 16 + row) * 1024 + h * 64 + cb * 8) =
            *(const bf16x8*)&Pm[(wq * 16 + row) * 72 + cb * 8];
    }
}

// ---------------------------------------------------------------------------
extern "C" void kernel_launch(void* const* d_in, const int* in_sizes, int n_in,
                              void* d_out, int out_size, void* d_ws, size_t ws_size,
                              hipStream_t stream)
{
    const float* x  = (const float*)d_in[0];
    const float* Wq = (const float*)d_in[1];
    const float* bq = (const float*)d_in[2];
    const float* Wk = (const float*)d_in[3];
    const float* bk = (const float*)d_in[4];
    const float* Wv = (const float*)d_in[5];
    const float* bv = (const float*)d_in[6];
    const float* Wo = (const float*)d_in[7];
    const float* nw = (const float*)d_in[8];
    float* out = (float*)d_out;

    const int D = 1024;
    const int M = in_sizes[0] / D;   // B*S = 4096

    unsigned short* xbb = (unsigned short*)d_ws;         // M*D
    unsigned short* Wqb = xbb + (size_t)M * D;           // D*D
    unsigned short* Wkb = Wqb + (size_t)D * D;
    unsigned short* Wvb = Wkb + (size_t)D * D;
    unsigned short* Wob = Wvb + (size_t)D * D;
    unsigned short* qbw = Wob + (size_t)D * D;           // M*D
    unsigned short* kbw = qbw + (size_t)M * D;
    unsigned short* vTw = kbw + (size_t)M * D;
    unsigned short* zbw = vTw + (size_t)M * D;

    const int nx4 = M * D / 4, nw4 = D * D / 4;
    const int ncvt = nx4 + 4 * nw4;
    cvt_all<<<(ncvt + 255) / 256, 256, 0, stream>>>(
        x, Wq, Wk, Wv, Wo, xbb, Wqb, Wkb, Wvb, Wob, nx4, nw4);

    gemm_qkv<<<dim3(D / 128, M / 128, 3), 256, 0, stream>>>(
        xbb, Wqb, Wkb, Wvb, bq, bk, bv, nw, qbw, kbw, vTw, M);

    attn_mfma<<<dim3(32, (M / 2048) * 16), 256, 0, stream>>>(qbw, kbw, vTw, zbw);

    gemm_out<<<dim3(D / 128, M / 128), 256, 0, stream>>>(zbw, Wob, x, out, M);
}